// Round 16
// baseline (126.764 us; speedup 1.0000x reference)
//
#include <hip/hip_runtime.h>
#include <hip/hip_bf16.h>
#include <math.h>

#define FREQS 9
#define DATA_DIM 28
#define WIDTH 128
#define IN_DIM 82
#define HST2 72      // shorts per sample row in H stripe (144 B) -> ~2-way conflicts
#define PEST 56      // f32 per W1_pe row in LDS (padded 54->56)

typedef float f32x4 __attribute__((ext_vector_type(4)));
typedef short s16x8 __attribute__((ext_vector_type(8)));

__device__ __forceinline__ short f2bf(float f) {
    unsigned u = __builtin_bit_cast(unsigned, f);
    u += 0x7fffu + ((u >> 16) & 1u);
    return (short)(u >> 16);
}

// native RNE pack -> v_cvt_pk_bf16_f32 (m240: don't hand-roll)
__device__ __forceinline__ unsigned pk2(float a, float b) {
    float2 t; t.x = a; t.y = b;
    __hip_bfloat162 h = __float22bfloat162_rn(t);
    unsigned r;
    __builtin_memcpy(&r, &h, sizeof(r));
    return r;
}

// coalesced global->LDS (16B/lane, lds dest = uniform base + lane*16)
__device__ __forceinline__ void gload_lds16(const void* g, void* l) {
    __builtin_amdgcn_global_load_lds(
        (const __attribute__((address_space(1))) unsigned int*)g,
        (__attribute__((address_space(3))) unsigned int*)l, 16, 0, 0);
}

// ws: [0] nz counter, [1] flag, [64..64+B) cnt, [64+B..64+2B) roff,
// then W1bf 128*32 bf16 (8KB), then hpe B*128 f32 (4MB).
// R13 lesson: packed order is the reference's flatnonzero order (b-major,
// n-ascending exclusive scan) — data rows are indexed by it. No atomic packing.

__global__ void k_count_bytes(const unsigned int* __restrict__ mw, int nwords, int* ws) {
    int tid = blockIdx.x * blockDim.x + threadIdx.x;
    int stride = gridDim.x * blockDim.x;
    int c = 0;
    for (int i = tid; i < nwords; i += stride) {
        unsigned int w = mw[i];
        c += ((w & 0xffu) != 0) + (((w >> 8) & 0xffu) != 0) +
             (((w >> 16) & 0xffu) != 0) + ((w >> 24) != 0);
    }
    __shared__ int red[256];
    red[threadIdx.x] = c;
    __syncthreads();
    for (int off = 128; off > 0; off >>= 1) {
        if (threadIdx.x < off) red[threadIdx.x] += red[threadIdx.x + off];
        __syncthreads();
    }
    if (threadIdx.x == 0) atomicAdd(&ws[0], red[0]);
}

__global__ void k_set_flag(int* ws, int P) { ws[1] = (ws[0] == P) ? 1 : 0; }

__global__ void k_ray_count(const void* __restrict__ maskp, const int* __restrict__ wsflag,
                            int* __restrict__ cnt, int N) {
    int b = blockIdx.x;
    int lane = threadIdx.x;
    int fl = wsflag[0];
    const unsigned char* m8 = (const unsigned char*)maskp;
    const int* m32 = (const int*)maskp;
    int base = 0;
    for (int t = 0; t < N / 64; ++t) {
        int n = t * 64 + lane;
        int mv = fl ? (int)m8[(size_t)b * N + n] : m32[(size_t)b * N + n];
        unsigned long long bal = __ballot(mv != 0);
        base += __popcll(bal);
    }
    if (lane == 0) cnt[b] = base;
}

__global__ void k_scan(const int* __restrict__ cnt, int* __restrict__ roff, int Bn) {
    __shared__ int sums[1024];
    int tid = threadIdx.x;
    int per = Bn / 1024;
    int loc[8];
    int s = 0;
    for (int i = 0; i < per; ++i) { loc[i] = s; s += cnt[tid * per + i]; }
    sums[tid] = s;
    __syncthreads();
    for (int off = 1; off < 1024; off <<= 1) {
        int t = sums[tid];
        int v = (tid >= off) ? sums[tid - off] : 0;
        __syncthreads();
        sums[tid] = t + v;
        __syncthreads();
    }
    int excl = sums[tid] - s;
    for (int i = 0; i < per; ++i) roff[tid * per + i] = excl + loc[i];
}

// hpe[b][row] = b1[row] + sum_j W1[row][28+j]*pe_b[j]; block 0 also fills W1bf.
__global__ __launch_bounds__(256) void k_hpe(
    const float* __restrict__ rays_d, const float* __restrict__ W1,
    const float* __restrict__ b1, short* __restrict__ W1bf,
    float* __restrict__ hpe, int Bn)
{
    __shared__ __align__(16) float w1pe[WIDTH * PEST];   // 28 KB
    __shared__ __align__(16) float pe_s[4][PEST];

    int tid = threadIdx.x;
    if (blockIdx.x == 0) {
        for (int t = tid; t < WIDTH * 32; t += 256) {
            int n = t / 32, k = t - n * 32;
            W1bf[t] = (k < DATA_DIM) ? f2bf(W1[n * IN_DIM + k]) : (short)0;
        }
    }
    for (int t = tid; t < WIDTH * PEST; t += 256) {
        int row = t / PEST, j = t - row * PEST;
        w1pe[t] = (j < 54) ? W1[row * IN_DIM + DATA_DIM + j] : 0.0f;
    }
    int wid = tid >> 6, lane = tid & 63;
    if (lane >= 54 && lane < PEST) pe_s[wid][lane] = 0.0f;
    __syncthreads();

    int raysPer = (Bn + gridDim.x - 1) / gridDim.x;
    for (int it = 0; it < raysPer; it += 4) {
        int b = blockIdx.x * raysPer + it + wid;
        if (b >= Bn) break;
        float dx = rays_d[b * 3 + 0], dy = rays_d[b * 3 + 1], dz = rays_d[b * 3 + 2];
        int idx = (lane < 54) ? lane : 0;
        int fb = idx / 6, t5 = idx - fb * 6;
        int ax = (t5 < 3) ? t5 : (t5 - 3);
        float dv = (ax == 0) ? dx : ((ax == 1) ? dy : dz);
        float ang = dv * (float)(1 << fb);
        float pev = (t5 < 3) ? sinf(ang) : cosf(ang);
        if (lane < 54) pe_s[wid][lane] = pev;

        #pragma unroll
        for (int rr = 0; rr < 2; ++rr) {
            int row = lane + 64 * rr;
            f32x4 s = {0.f, 0.f, 0.f, 0.f};
            #pragma unroll
            for (int j = 0; j < PEST; j += 4) {
                f32x4 wv = *reinterpret_cast<const f32x4*>(&w1pe[row * PEST + j]);
                f32x4 pv = *reinterpret_cast<const f32x4*>(&pe_s[wid][j]);
                s += wv * pv;
            }
            hpe[(size_t)b * WIDTH + row] = b1[row] + (s[0] + s[1]) + (s[2] + s[3]);
        }
    }
}

// ===== Fused render: block = ray (128 thr, 2 waves). Wave w does batches {w, w+2};
// MLP via MFMA with coalesced LDS staging; wave 0 epilogue does the composite.
// (128,3): cap 170 regs >= live ~124 (spill guard: WRITE_SIZE).
__global__ __launch_bounds__(128, 3) void k_render(
    const float* __restrict__ rays_d, const float* __restrict__ intrs,
    const void* __restrict__ maskp, const float* __restrict__ data,
    const short* __restrict__ W1bf, const float* __restrict__ W2,
    const float* __restrict__ b2, const float* __restrict__ hpe,
    const int* __restrict__ wsflag, const int* __restrict__ roff,
    float* __restrict__ out, int Bn, int N, int P)
{
    int wid = threadIdx.x >> 6;
    int lane = threadIdx.x & 63;
    int b = blockIdx.x;
    int g = lane >> 4, c = lane & 15;

    float* out_comp = out;
    float* out_alpha = out + (size_t)Bn * 3;

    __shared__ __align__(16) short stageH[2][64 * HST2];  // 18.4 KB (stage 7168B ⊂ 9216B)
    __shared__ __align__(16) float pre_s[256][4];         // 4 KB
    __shared__ int nlist[256];
    __shared__ int cnt_s;

    int fl = wsflag[0];
    const unsigned char* m8 = (const unsigned char*)maskp;
    const int* m32 = (const int*)maskp;

    // Phase A (wave 0): masked-n list, count, zero unmasked alpha.
    if (wid == 0) {
        int base = 0;
        for (int t = 0; t < N / 64; ++t) {
            int n = t * 64 + lane;
            int mv = fl ? (int)m8[(size_t)b * N + n] : m32[(size_t)b * N + n];
            bool m = (mv != 0);
            unsigned long long bal = __ballot(m);
            int rank = __popcll(bal & ((1ull << lane) - 1ull));
            if (m) nlist[base + rank] = n;
            else   out_alpha[(size_t)b * N + n] = 0.0f;
            base += __popcll(bal);
        }
        if (lane == 0) cnt_s = base;
    }

    // W2 A-fragments (independent of phase A)
    s16x8 w2f[4];
    #pragma unroll
    for (int ks = 0; ks < 4; ++ks) {
        if (c < 4) {
            const float* wp = W2 + c * WIDTH + 32 * ks + 8 * g;
            f32x4 u = *reinterpret_cast<const f32x4*>(wp);
            f32x4 v = *reinterpret_cast<const f32x4*>(wp + 4);
            #pragma unroll
            for (int j = 0; j < 4; ++j) {
                w2f[ks][j] = f2bf(u[j]);
                w2f[ks][4 + j] = f2bf(v[j]);
            }
        } else {
            #pragma unroll
            for (int j = 0; j < 8; ++j) w2f[ks][j] = 0;
        }
    }

    __syncthreads();
    int cnt = cnt_s;
    int nb = (cnt + 63) >> 6;          // <=4 for N=256
    int poff = roff[b];

    const s16x8* W1v = reinterpret_cast<const s16x8*>(W1bf);
    const float* hpeB = hpe + (size_t)b * WIDTH;
    short* hb = &stageH[wid][0];
    size_t maxoff = (size_t)P * 112 - 16;

    for (int bt = wid; bt < nb; bt += 2) {
        int s0 = poff + 64 * bt;

        // coalesced stage: 64 data rows (7168 B) into this wave's slice
        #pragma unroll
        for (int ci = 0; ci < 7; ++ci) {
            size_t off = (size_t)s0 * 112 + (size_t)ci * 1024 + (size_t)lane * 16;
            if (off > maxoff) off = maxoff;
            gload_lds16((const char*)data + off, (char*)hb + ci * 1024);
        }
        asm volatile("s_waitcnt vmcnt(0)" ::: "memory");

        // X B-fragments from LDS
        const float* hbf = reinterpret_cast<const float*>(hb);
        s16x8 a0[4];
        #pragma unroll
        for (int mb = 0; mb < 4; ++mb) {
            int row = 16 * mb + c;
            unsigned u0, u1, u2, u3;
            if (g < 3) {
                f32x4 lo = *reinterpret_cast<const f32x4*>(hbf + row * 28 + 8 * g);
                f32x4 hi = *reinterpret_cast<const f32x4*>(hbf + row * 28 + 8 * g + 4);
                u0 = pk2(lo[0], lo[1]); u1 = pk2(lo[2], lo[3]);
                u2 = pk2(hi[0], hi[1]); u3 = pk2(hi[2], hi[3]);
            } else {
                f32x4 lo = *reinterpret_cast<const f32x4*>(hbf + row * 28 + 24);
                u0 = pk2(lo[0], lo[1]); u1 = pk2(lo[2], lo[3]);
                u2 = 0; u3 = 0;
            }
            uint4 uu; uu.x = u0; uu.y = u1; uu.z = u2; uu.w = u3;
            a0[mb] = __builtin_bit_cast(s16x8, uu);
        }

        f32x4 D[4];
        #pragma unroll
        for (int t = 0; t < 4; ++t) D[t] = (f32x4){0.f, 0.f, 0.f, 0.f};

        #pragma unroll
        for (int ms = 0; ms < 2; ++ms) {
            #pragma unroll
            for (int hh = 0; hh < 4; ++hh) {
                int nt = 4 * ms + hh;
                s16x8 Bk0 = W1v[(16 * nt + c) * 4 + g];   // 8KB, L1-resident

                f32x4 C0 = {0.f,0.f,0.f,0.f}, C1 = C0, C2 = C0, C3 = C0;
                C0 = __builtin_amdgcn_mfma_f32_16x16x32_bf16(Bk0, a0[0], C0, 0, 0, 0);
                C1 = __builtin_amdgcn_mfma_f32_16x16x32_bf16(Bk0, a0[1], C1, 0, 0, 0);
                C2 = __builtin_amdgcn_mfma_f32_16x16x32_bf16(Bk0, a0[2], C2, 0, 0, 0);
                C3 = __builtin_amdgcn_mfma_f32_16x16x32_bf16(Bk0, a0[3], C3, 0, 0, 0);

                // ray-uniform hpe (broadcast load), relu, bf16, H stripe
                f32x4 hv = *reinterpret_cast<const f32x4*>(hpeB + 16 * nt + 4 * g);
                f32x4 Cm[4] = {C0, C1, C2, C3};
                #pragma unroll
                for (int mb = 0; mb < 4; ++mb) {
                    uint2 w;
                    w.x = pk2(fmaxf(Cm[mb][0] + hv[0], 0.f), fmaxf(Cm[mb][1] + hv[1], 0.f));
                    w.y = pk2(fmaxf(Cm[mb][2] + hv[2], 0.f), fmaxf(Cm[mb][3] + hv[3], 0.f));
                    *reinterpret_cast<uint2*>(&hb[(16 * mb + c) * HST2 + 16 * hh + 4 * g]) = w;
                }
            }
            #pragma unroll
            for (int ks2 = 0; ks2 < 2; ++ks2) {
                #pragma unroll
                for (int t = 0; t < 4; ++t) {
                    s16x8 Bf = *reinterpret_cast<const s16x8*>(
                        &hb[(16 * t + c) * HST2 + 32 * ks2 + 8 * g]);
                    D[t] = __builtin_amdgcn_mfma_f32_16x16x32_bf16(w2f[2 * ms + ks2], Bf, D[t], 0, 0, 0);
                }
            }
        }

        // preact (f32) to LDS: sample-in-ray = 64*bt + 16t + c (g==0 lanes own rows)
        if (g == 0) {
            #pragma unroll
            for (int t = 0; t < 4; ++t)
                *reinterpret_cast<f32x4*>(&pre_s[64 * bt + 16 * t + c][0]) = D[t];
        }
        // drain LDS reads before next batch's stage overwrites hb
        asm volatile("s_waitcnt lgkmcnt(0)" ::: "memory");
    }

    __syncthreads();

    // Phase C (wave 0): composite over nb batches sequentially
    if (wid == 0) {
        float dx = rays_d[b * 3 + 0], dy = rays_d[b * 3 + 1], dz = rays_d[b * 3 + 2];
        float nrm = sqrtf(dx * dx + dy * dy + dz * dz);
        f32x4 b2v = *reinterpret_cast<const f32x4*>(b2);

        float T = 1.0f;
        float aR = 0.f, aG = 0.f, aB = 0.f, aA = 0.f;

        for (int j = 0; j < nb; ++j) {
            int r = 64 * j + lane;
            bool act = (r < cnt);
            int rc = act ? r : 0;
            f32x4 pv = *reinterpret_cast<const f32x4*>(&pre_s[rc][0]);
            int n = nlist[rc];

            float p0 = pv[0] + b2v[0];
            float p1 = pv[1] + b2v[1];
            float p2 = pv[2] + b2v[2];
            float p3 = pv[3] + b2v[3];

            float density = fmaxf(p0, 0.0f);
            float dist = (intrs[(size_t)b * (N + 1) + n + 1] - intrs[(size_t)b * (N + 1) + n]) * nrm;
            float alpha = act ? (1.0f - expf(-density * dist)) : 0.0f;

            float fct = 1.0f - alpha + 1e-10f;
            float scan = fct;
            #pragma unroll
            for (int d = 1; d < 64; d <<= 1) {
                float o = __shfl_up(scan, d, 64);
                if (lane >= d) scan *= o;
            }
            float tot  = __shfl(scan, 63, 64);
            float excl = __shfl_up(scan, 1, 64);
            if (lane == 0) excl = 1.0f;

            float cum  = T * excl;
            float absl = alpha * cum;
            float sR = 1.0f / (1.0f + expf(-p1));
            float sG = 1.0f / (1.0f + expf(-p2));
            float sB = 1.0f / (1.0f + expf(-p3));
            aR = fmaf(absl, sR, aR);
            aG = fmaf(absl, sG, aG);
            aB = fmaf(absl, sB, aB);
            aA += absl;
            T *= tot;

            if (act) out_alpha[(size_t)b * N + n] = alpha;
        }

        #pragma unroll
        for (int d = 32; d > 0; d >>= 1) {
            aR += __shfl_down(aR, d, 64);
            aG += __shfl_down(aG, d, 64);
            aB += __shfl_down(aB, d, 64);
            aA += __shfl_down(aA, d, 64);
        }
        if (lane == 0) {
            out_comp[b * 3 + 0] = aR + (1.0f - aA);
            out_comp[b * 3 + 1] = aG + (1.0f - aA);
            out_comp[b * 3 + 2] = aB + (1.0f - aA);
        }
    }
}

extern "C" void kernel_launch(void* const* d_in, const int* in_sizes, int n_in,
                              void* d_out, int out_size, void* d_ws, size_t ws_size,
                              hipStream_t stream) {
    const float* rays_d = (const float*)d_in[0];
    const float* intrs  = (const float*)d_in[1];
    const void*  maskp  = d_in[2];
    const float* data   = (const float*)d_in[3];
    const float* W1     = (const float*)d_in[4];
    const float* b1     = (const float*)d_in[5];
    const float* W2     = (const float*)d_in[6];
    const float* b2     = (const float*)d_in[7];
    float* out = (float*)d_out;

    int B = in_sizes[0] / 3;            // 8192
    int N = in_sizes[2] / B;            // 256
    int P = in_sizes[3] / DATA_DIM;     // packed sample count

    int* wsI    = (int*)d_ws;
    int* cnt    = wsI + 64;
    int* roff   = wsI + 64 + B;
    short* W1bf = (short*)(wsI + 64 + 2 * B);         // 8 KB
    float* hpe  = (float*)(W1bf + WIDTH * 32);        // B*128 f32 = 4 MB

    hipMemsetAsync(d_ws, 0, 256, stream);
    int nwords = (B * N) / 4;
    k_count_bytes<<<256, 256, 0, stream>>>((const unsigned int*)maskp, nwords, wsI);
    k_set_flag<<<1, 1, 0, stream>>>(wsI, P);
    k_ray_count<<<B, 64, 0, stream>>>(maskp, wsI + 1, cnt, N);
    k_scan<<<1, 1024, 0, stream>>>(cnt, roff, B);
    k_hpe<<<256, 256, 0, stream>>>(rays_d, W1, b1, W1bf, hpe, B);
    k_render<<<B, 128, 0, stream>>>(rays_d, intrs, maskp, data, W1bf, W2, b2, hpe,
                                    wsI + 1, roff, out, B, N, P);
}

// Round 17
// 118.472 us; speedup vs baseline: 1.0700x; 1.0700x over previous
//
#include <hip/hip_runtime.h>
#include <hip/hip_bf16.h>
#include <math.h>

#define FREQS 9
#define DATA_DIM 28
#define WIDTH 128
#define IN_DIM 82
#define HST2 72      // shorts per sample row in H stripe (144 B) -> ~2-way conflicts
#define W1ST 40      // shorts per W1 row in LDS (80 B) -> ~2-way conflicts
#define PEST 56      // f32 per W1_pe row in LDS (padded 54->56)

typedef float f32x4 __attribute__((ext_vector_type(4)));
typedef short s16x8 __attribute__((ext_vector_type(8)));

__device__ __forceinline__ short f2bf(float f) {
    unsigned u = __builtin_bit_cast(unsigned, f);
    u += 0x7fffu + ((u >> 16) & 1u);
    return (short)(u >> 16);
}

// native RNE pack -> v_cvt_pk_bf16_f32 (m240: don't hand-roll)
__device__ __forceinline__ unsigned pk2(float a, float b) {
    float2 t; t.x = a; t.y = b;
    __hip_bfloat162 h = __float22bfloat162_rn(t);
    unsigned r;
    __builtin_memcpy(&r, &h, sizeof(r));
    return r;
}

__device__ __forceinline__ float bf2f(unsigned u16v) {
    unsigned u = u16v << 16;
    return __builtin_bit_cast(float, u);
}

// coalesced global->LDS (16B/lane, lds dest = uniform base + lane*16)
__device__ __forceinline__ void gload_lds16(const void* g, void* l) {
    __builtin_amdgcn_global_load_lds(
        (const __attribute__((address_space(1))) unsigned int*)g,
        (__attribute__((address_space(3))) unsigned int*)l, 16, 0, 0);
}

// ws: [0] nz-byte counter; [64..64+B) cnt, [64+B..64+2B) roff,
// then W1bf 128*32 bf16 (8KB), hpe B*128 f32 (4MB), preact P uint2 (8MB).
// R13 lesson: packed order is the reference's flatnonzero order (b-major,
// n-ascending exclusive scan) — data rows are indexed by it. No atomic packing.
// Mask width detected safely: count nonzero in first B*N BYTES (valid under
// both layouts); ==P -> 1-byte storage. m32 is only read after flag known.

__global__ void k_count_bytes(const unsigned int* __restrict__ mw, int nwords, int* ws) {
    int tid = blockIdx.x * blockDim.x + threadIdx.x;
    int stride = gridDim.x * blockDim.x;
    int c = 0;
    for (int i = tid; i < nwords; i += stride) {
        unsigned int w = mw[i];
        c += ((w & 0xffu) != 0) + (((w >> 8) & 0xffu) != 0) +
             (((w >> 16) & 0xffu) != 0) + ((w >> 24) != 0);
    }
    __shared__ int red[256];
    red[threadIdx.x] = c;
    __syncthreads();
    for (int off = 128; off > 0; off >>= 1) {
        if (threadIdx.x < off) red[threadIdx.x] += red[threadIdx.x + off];
        __syncthreads();
    }
    if (threadIdx.x == 0) atomicAdd(&ws[0], red[0]);
}

// per-ray masked count (flag computed locally from finalized ws[0])
__global__ void k_cnt(const void* __restrict__ maskp, const int* __restrict__ wsTot,
                      int P, int* __restrict__ cnt, int N) {
    int b = blockIdx.x;
    int lane = threadIdx.x;
    int fl = (wsTot[0] == P);
    const unsigned char* m8 = (const unsigned char*)maskp;
    const int* m32 = (const int*)maskp;
    int base = 0;
    for (int t = 0; t < N / 64; ++t) {
        int n = t * 64 + lane;
        int mv = fl ? (int)m8[(size_t)b * N + n] : m32[(size_t)b * N + n];
        unsigned long long bal = __ballot(mv != 0);
        base += __popcll(bal);
    }
    if (lane == 0) cnt[b] = base;
}

__global__ void k_scan(const int* __restrict__ cnt, int* __restrict__ roff, int Bn) {
    __shared__ int sums[1024];
    int tid = threadIdx.x;
    int per = Bn / 1024;
    int loc[8];
    int s = 0;
    for (int i = 0; i < per; ++i) { loc[i] = s; s += cnt[tid * per + i]; }
    sums[tid] = s;
    __syncthreads();
    for (int off = 1; off < 1024; off <<= 1) {
        int t = sums[tid];
        int v = (tid >= off) ? sums[tid - off] : 0;
        __syncthreads();
        sums[tid] = t + v;
        __syncthreads();
    }
    int excl = sums[tid] - s;
    for (int i = 0; i < per; ++i) roff[tid * per + i] = excl + loc[i];
}

// hpe[b][row] = b1[row] + sum_j W1[row][28+j]*pe_b[j]; block 0 also fills W1bf.
__global__ __launch_bounds__(256) void k_hpe(
    const float* __restrict__ rays_d, const float* __restrict__ W1,
    const float* __restrict__ b1, short* __restrict__ W1bf,
    float* __restrict__ hpe, int Bn)
{
    __shared__ __align__(16) float w1pe[WIDTH * PEST];   // 28 KB
    __shared__ __align__(16) float pe_s[4][PEST];

    int tid = threadIdx.x;
    if (blockIdx.x == 0) {
        for (int t = tid; t < WIDTH * 32; t += 256) {
            int n = t / 32, k = t - n * 32;
            W1bf[t] = (k < DATA_DIM) ? f2bf(W1[n * IN_DIM + k]) : (short)0;
        }
    }
    for (int t = tid; t < WIDTH * PEST; t += 256) {
        int row = t / PEST, j = t - row * PEST;
        w1pe[t] = (j < 54) ? W1[row * IN_DIM + DATA_DIM + j] : 0.0f;
    }
    int wid = tid >> 6, lane = tid & 63;
    if (lane >= 54 && lane < PEST) pe_s[wid][lane] = 0.0f;
    __syncthreads();

    int raysPer = (Bn + gridDim.x - 1) / gridDim.x;
    for (int it = 0; it < raysPer; it += 4) {
        int b = blockIdx.x * raysPer + it + wid;
        if (b >= Bn) break;
        float dx = rays_d[b * 3 + 0], dy = rays_d[b * 3 + 1], dz = rays_d[b * 3 + 2];
        int idx = (lane < 54) ? lane : 0;
        int fb = idx / 6, t5 = idx - fb * 6;
        int ax = (t5 < 3) ? t5 : (t5 - 3);
        float dv = (ax == 0) ? dx : ((ax == 1) ? dy : dz);
        float ang = dv * (float)(1 << fb);
        float pev = (t5 < 3) ? sinf(ang) : cosf(ang);
        if (lane < 54) pe_s[wid][lane] = pev;

        #pragma unroll
        for (int rr = 0; rr < 2; ++rr) {
            int row = lane + 64 * rr;
            f32x4 s = {0.f, 0.f, 0.f, 0.f};
            #pragma unroll
            for (int j = 0; j < PEST; j += 4) {
                f32x4 wv = *reinterpret_cast<const f32x4*>(&w1pe[row * PEST + j]);
                f32x4 pv = *reinterpret_cast<const f32x4*>(&pe_s[wid][j]);
                s += wv * pv;
            }
            hpe[(size_t)b * WIDTH + row] = b1[row] + (s[0] + s[1]) + (s[2] + s[3]);
        }
    }
}

// ===== Phase 1: MLP. Block = 2 rays (4 waves); wave (wid) handles batches
// bt = (wid&1), (wid&1)+2 of ray bid*2+(wid>>1). Ray id is wave-uniform ->
// hpe loads are broadcast; W1 fragments from LDS; data staged via gload_lds.
// (256,3): proven no-spill point (R10/R12/R14/R15).
__global__ __launch_bounds__(256, 3) void k_mlp(
    const float* __restrict__ data, const short* __restrict__ W1bf,
    const float* __restrict__ W2, const float* __restrict__ hpe,
    const int* __restrict__ cnt, const int* __restrict__ roff,
    uint2* __restrict__ preact, int P)
{
    int tid = threadIdx.x;
    int wid = tid >> 6;
    int lane = tid & 63;
    int g = lane >> 4, c = lane & 15;

    // XCD-aware swizzle (T1): consecutive rays per XCD -> hpe/data L2 locality.
    int nwg = gridDim.x;
    int bid = blockIdx.x;
    {
        int q = nwg / 8, r = nwg % 8;
        int xcd = bid % 8, off = bid / 8;
        bid = (xcd < r ? xcd * (q + 1) : r * (q + 1) + (xcd - r) * q) + off;
    }
    int ray = bid * 2 + (wid >> 1);
    int bt0 = wid & 1;

    __shared__ __align__(16) short stageH[4][64 * HST2];  // 36.9 KB
    __shared__ __align__(16) short w1s[WIDTH * W1ST];     // 10 KB

    // Stage W1bf (K=32, padded stride) into LDS once per block.
    for (int t = tid; t < WIDTH * 4; t += 256) {
        int row = t >> 2, seg = t & 3;
        *reinterpret_cast<f32x4*>(&w1s[row * W1ST + seg * 8]) =
            *reinterpret_cast<const f32x4*>(W1bf + row * 32 + seg * 8);
    }

    // W2 A-fragments (per-lane constant)
    s16x8 w2f[4];
    #pragma unroll
    for (int ks = 0; ks < 4; ++ks) {
        if (c < 4) {
            const float* wp = W2 + c * WIDTH + 32 * ks + 8 * g;
            f32x4 u = *reinterpret_cast<const f32x4*>(wp);
            f32x4 v = *reinterpret_cast<const f32x4*>(wp + 4);
            #pragma unroll
            for (int j = 0; j < 4; ++j) {
                w2f[ks][j] = f2bf(u[j]);
                w2f[ks][4 + j] = f2bf(v[j]);
            }
        } else {
            #pragma unroll
            for (int j = 0; j < 8; ++j) w2f[ks][j] = 0;
        }
    }

    __syncthreads();

    int cn = cnt[ray];
    int poff = roff[ray];
    int nb = (cn + 63) >> 6;           // <=4 for N=256
    const float* hpeB = hpe + (size_t)ray * WIDTH;
    short* hb = &stageH[wid][0];
    size_t maxoff = (size_t)P * 112 - 16;

    for (int bt = bt0; bt < nb; bt += 2) {
        int s0 = poff + 64 * bt;

        // coalesced stage: 64 data rows (7168 B) into this wave's slice
        #pragma unroll
        for (int ci = 0; ci < 7; ++ci) {
            size_t off = (size_t)s0 * 112 + (size_t)ci * 1024 + (size_t)lane * 16;
            if (off > maxoff) off = maxoff;
            gload_lds16((const char*)data + off, (char*)hb + ci * 1024);
        }
        asm volatile("s_waitcnt vmcnt(0)" ::: "memory");

        // X B-fragments from LDS
        const float* hbf = reinterpret_cast<const float*>(hb);
        s16x8 a0[4];
        #pragma unroll
        for (int mb = 0; mb < 4; ++mb) {
            int row = 16 * mb + c;
            unsigned u0, u1, u2, u3;
            if (g < 3) {
                f32x4 lo = *reinterpret_cast<const f32x4*>(hbf + row * 28 + 8 * g);
                f32x4 hi = *reinterpret_cast<const f32x4*>(hbf + row * 28 + 8 * g + 4);
                u0 = pk2(lo[0], lo[1]); u1 = pk2(lo[2], lo[3]);
                u2 = pk2(hi[0], hi[1]); u3 = pk2(hi[2], hi[3]);
            } else {
                f32x4 lo = *reinterpret_cast<const f32x4*>(hbf + row * 28 + 24);
                u0 = pk2(lo[0], lo[1]); u1 = pk2(lo[2], lo[3]);
                u2 = 0; u3 = 0;
            }
            uint4 uu; uu.x = u0; uu.y = u1; uu.z = u2; uu.w = u3;
            a0[mb] = __builtin_bit_cast(s16x8, uu);
        }

        f32x4 D[4];
        #pragma unroll
        for (int t = 0; t < 4; ++t) D[t] = (f32x4){0.f, 0.f, 0.f, 0.f};

        #pragma unroll
        for (int ms = 0; ms < 2; ++ms) {
            #pragma unroll
            for (int hh = 0; hh < 4; ++hh) {
                int nt = 4 * ms + hh;
                s16x8 Bk0 = *reinterpret_cast<const s16x8*>(&w1s[(16 * nt + c) * W1ST + 8 * g]);

                f32x4 C0 = {0.f,0.f,0.f,0.f}, C1 = C0, C2 = C0, C3 = C0;
                C0 = __builtin_amdgcn_mfma_f32_16x16x32_bf16(Bk0, a0[0], C0, 0, 0, 0);
                C1 = __builtin_amdgcn_mfma_f32_16x16x32_bf16(Bk0, a0[1], C1, 0, 0, 0);
                C2 = __builtin_amdgcn_mfma_f32_16x16x32_bf16(Bk0, a0[2], C2, 0, 0, 0);
                C3 = __builtin_amdgcn_mfma_f32_16x16x32_bf16(Bk0, a0[3], C3, 0, 0, 0);

                // ray-uniform hpe: broadcast load (4 distinct addrs per wave)
                f32x4 hv = *reinterpret_cast<const f32x4*>(hpeB + 16 * nt + 4 * g);
                f32x4 Cm[4] = {C0, C1, C2, C3};
                #pragma unroll
                for (int mb = 0; mb < 4; ++mb) {
                    uint2 w;
                    w.x = pk2(fmaxf(Cm[mb][0] + hv[0], 0.f), fmaxf(Cm[mb][1] + hv[1], 0.f));
                    w.y = pk2(fmaxf(Cm[mb][2] + hv[2], 0.f), fmaxf(Cm[mb][3] + hv[3], 0.f));
                    *reinterpret_cast<uint2*>(&hb[(16 * mb + c) * HST2 + 16 * hh + 4 * g]) = w;
                }
            }
            #pragma unroll
            for (int ks2 = 0; ks2 < 2; ++ks2) {
                #pragma unroll
                for (int t = 0; t < 4; ++t) {
                    s16x8 Bf = *reinterpret_cast<const s16x8*>(
                        &hb[(16 * t + c) * HST2 + 32 * ks2 + 8 * g]);
                    D[t] = __builtin_amdgcn_mfma_f32_16x16x32_bf16(w2f[2 * ms + ks2], Bf, D[t], 0, 0, 0);
                }
            }
        }

        // store preact (bf16 x4) for in-range samples; g==0 lanes own rows
        if (g == 0) {
            #pragma unroll
            for (int t = 0; t < 4; ++t) {
                int r = 64 * bt + 16 * t + c;
                if (r < cn) {
                    uint2 w;
                    w.x = pk2(D[t][0], D[t][1]);
                    w.y = pk2(D[t][2], D[t][3]);
                    preact[poff + r] = w;
                }
            }
        }
        // drain LDS reads before next batch's stage overwrites hb
        asm volatile("s_waitcnt lgkmcnt(0)" ::: "memory");
    }
}

// ===== Phase 2: per-ray composite (wave per ray); nlist rebuilt from mask =====
__global__ __launch_bounds__(256) void k_comp(
    const float* __restrict__ rays_d, const float* __restrict__ intrs,
    const void* __restrict__ maskp, const uint2* __restrict__ preact,
    const int* __restrict__ roff, const float* __restrict__ b2,
    const int* __restrict__ wsTot, int P,
    float* __restrict__ out, int Bn, int N)
{
    int wid = threadIdx.x >> 6;
    int lane = threadIdx.x & 63;
    int b = blockIdx.x * 4 + wid;

    float* out_comp = out;
    float* out_alpha = out + (size_t)Bn * 3;

    __shared__ int nlist[4][256];

    int fl = (wsTot[0] == P);
    const unsigned char* m8 = (const unsigned char*)maskp;
    const int* m32 = (const int*)maskp;

    // rebuild masked-n list; zero alpha for unmasked
    int base = 0;
    for (int t = 0; t < N / 64; ++t) {
        int n = t * 64 + lane;
        int mv = fl ? (int)m8[(size_t)b * N + n] : m32[(size_t)b * N + n];
        bool m = (mv != 0);
        unsigned long long bal = __ballot(m);
        int rank = __popcll(bal & ((1ull << lane) - 1ull));
        if (m) nlist[wid][base + rank] = n;
        else   out_alpha[(size_t)b * N + n] = 0.0f;
        base += __popcll(bal);
    }
    int cn = base;
    int poff = roff[b];

    float dx = rays_d[b * 3 + 0], dy = rays_d[b * 3 + 1], dz = rays_d[b * 3 + 2];
    float nrm = sqrtf(dx * dx + dy * dy + dz * dz);
    f32x4 b2v = *reinterpret_cast<const f32x4*>(b2);

    float T = 1.0f;
    float aR = 0.f, aG = 0.f, aB = 0.f, aA = 0.f;

    for (int r0 = 0; r0 < cn; r0 += 64) {
        int r = r0 + lane;
        bool act = (r < cn);
        int rc = act ? r : 0;
        uint2 pv = preact[poff + rc];
        int n = nlist[wid][rc];

        float p0 = bf2f(pv.x & 0xffffu) + b2v[0];
        float p1 = bf2f(pv.x >> 16)     + b2v[1];
        float p2 = bf2f(pv.y & 0xffffu) + b2v[2];
        float p3 = bf2f(pv.y >> 16)     + b2v[3];

        float density = fmaxf(p0, 0.0f);
        float dist = (intrs[(size_t)b * (N + 1) + n + 1] - intrs[(size_t)b * (N + 1) + n]) * nrm;
        float alpha = act ? (1.0f - expf(-density * dist)) : 0.0f;

        float fct = 1.0f - alpha + 1e-10f;
        float scan = fct;
        #pragma unroll
        for (int d = 1; d < 64; d <<= 1) {
            float o = __shfl_up(scan, d, 64);
            if (lane >= d) scan *= o;
        }
        float tot  = __shfl(scan, 63, 64);
        float excl = __shfl_up(scan, 1, 64);
        if (lane == 0) excl = 1.0f;

        float cum  = T * excl;
        float absl = alpha * cum;
        float sR = 1.0f / (1.0f + expf(-p1));
        float sG = 1.0f / (1.0f + expf(-p2));
        float sB = 1.0f / (1.0f + expf(-p3));
        aR = fmaf(absl, sR, aR);
        aG = fmaf(absl, sG, aG);
        aB = fmaf(absl, sB, aB);
        aA += absl;
        T *= tot;

        if (act) out_alpha[(size_t)b * N + n] = alpha;
    }

    #pragma unroll
    for (int d = 32; d > 0; d >>= 1) {
        aR += __shfl_down(aR, d, 64);
        aG += __shfl_down(aG, d, 64);
        aB += __shfl_down(aB, d, 64);
        aA += __shfl_down(aA, d, 64);
    }
    if (lane == 0) {
        out_comp[b * 3 + 0] = aR + (1.0f - aA);
        out_comp[b * 3 + 1] = aG + (1.0f - aA);
        out_comp[b * 3 + 2] = aB + (1.0f - aA);
    }
}

extern "C" void kernel_launch(void* const* d_in, const int* in_sizes, int n_in,
                              void* d_out, int out_size, void* d_ws, size_t ws_size,
                              hipStream_t stream) {
    const float* rays_d = (const float*)d_in[0];
    const float* intrs  = (const float*)d_in[1];
    const void*  maskp  = d_in[2];
    const float* data   = (const float*)d_in[3];
    const float* W1     = (const float*)d_in[4];
    const float* b1     = (const float*)d_in[5];
    const float* W2     = (const float*)d_in[6];
    const float* b2     = (const float*)d_in[7];
    float* out = (float*)d_out;

    int B = in_sizes[0] / 3;            // 8192
    int N = in_sizes[2] / B;            // 256
    int P = in_sizes[3] / DATA_DIM;     // packed sample count

    int* wsI    = (int*)d_ws;
    int* cnt    = wsI + 64;
    int* roff   = wsI + 64 + B;
    short* W1bf = (short*)(wsI + 64 + 2 * B);         // 8 KB
    float* hpe  = (float*)(W1bf + WIDTH * 32);        // B*128 f32 = 4 MB
    uint2* preact = (uint2*)(hpe + (size_t)B * WIDTH);  // P uint2 = 8 MB

    hipMemsetAsync(d_ws, 0, 64, stream);
    int nwords = (B * N) / 4;
    k_count_bytes<<<256, 256, 0, stream>>>((const unsigned int*)maskp, nwords, wsI);
    k_cnt<<<B, 64, 0, stream>>>(maskp, wsI, P, cnt, N);
    k_scan<<<1, 1024, 0, stream>>>(cnt, roff, B);
    k_hpe<<<256, 256, 0, stream>>>(rays_d, W1, b1, W1bf, hpe, B);
    k_mlp<<<B / 2, 256, 0, stream>>>(data, W1bf, W2, hpe, cnt, roff, preact, P);
    k_comp<<<B / 4, 256, 0, stream>>>(rays_d, intrs, maskp, preact, roff, b2,
                                      wsI, P, out, B, N);
}

// Round 18
// 105.518 us; speedup vs baseline: 1.2014x; 1.1228x over previous
//
#include <hip/hip_runtime.h>
#include <hip/hip_bf16.h>
#include <math.h>

#define FREQS 9
#define DATA_DIM 28
#define WIDTH 128
#define IN_DIM 82
#define HST2 72      // shorts per sample row in H stripe (144 B) -> ~2-way conflicts
#define PEST 56      // f32 per W1_pe row in LDS (padded 54->56)

typedef float f32x4 __attribute__((ext_vector_type(4)));
typedef short s16x8 __attribute__((ext_vector_type(8)));

__device__ __forceinline__ short f2bf(float f) {
    unsigned u = __builtin_bit_cast(unsigned, f);
    u += 0x7fffu + ((u >> 16) & 1u);
    return (short)(u >> 16);
}

// native RNE pack -> v_cvt_pk_bf16_f32 (m240: don't hand-roll)
__device__ __forceinline__ unsigned pk2(float a, float b) {
    float2 t; t.x = a; t.y = b;
    __hip_bfloat162 h = __float22bfloat162_rn(t);
    unsigned r;
    __builtin_memcpy(&r, &h, sizeof(r));
    return r;
}

__device__ __forceinline__ float bf2f(unsigned u16v) {
    unsigned u = u16v << 16;
    return __builtin_bit_cast(float, u);
}

// coalesced global->LDS (16B/lane, lds dest = uniform base + lane*16)
__device__ __forceinline__ void gload_lds16(const void* g, void* l) {
    __builtin_amdgcn_global_load_lds(
        (const __attribute__((address_space(1))) unsigned int*)g,
        (__attribute__((address_space(3))) unsigned int*)l, 16, 0, 0);
}

// ws: [0] nz-byte counter; [64..64+B) cnt, [64+B..64+2B) roff,
// then W1bf 128*32 bf16 (8KB), hpe B*128 f32 (4MB), packid P u32, preact P uint2.
// R13 lesson: packed order is the reference's flatnonzero order (b-major,
// n-ascending exclusive scan). R17 lesson: flat sample-indexed batches beat
// ray-aligned (per-ray rounding +25% work, wave imbalance).

__global__ void k_count_bytes(const unsigned int* __restrict__ mw, int nwords, int* ws) {
    int tid = blockIdx.x * blockDim.x + threadIdx.x;
    int stride = gridDim.x * blockDim.x;
    int c = 0;
    for (int i = tid; i < nwords; i += stride) {
        unsigned int w = mw[i];
        c += ((w & 0xffu) != 0) + (((w >> 8) & 0xffu) != 0) +
             (((w >> 16) & 0xffu) != 0) + ((w >> 24) != 0);
    }
    __shared__ int red[256];
    red[threadIdx.x] = c;
    __syncthreads();
    for (int off = 128; off > 0; off >>= 1) {
        if (threadIdx.x < off) red[threadIdx.x] += red[threadIdx.x + off];
        __syncthreads();
    }
    if (threadIdx.x == 0) atomicAdd(&ws[0], red[0]);
}

// per-ray masked count (mask width flag computed inline from ws[0])
__global__ void k_cnt(const void* __restrict__ maskp, const int* __restrict__ wsTot,
                      int P, int* __restrict__ cnt, int N) {
    int b = blockIdx.x;
    int lane = threadIdx.x;
    int fl = (wsTot[0] == P);
    const unsigned char* m8 = (const unsigned char*)maskp;
    const int* m32 = (const int*)maskp;
    int base = 0;
    for (int t = 0; t < N / 64; ++t) {
        int n = t * 64 + lane;
        int mv = fl ? (int)m8[(size_t)b * N + n] : m32[(size_t)b * N + n];
        unsigned long long bal = __ballot(mv != 0);
        base += __popcll(bal);
    }
    if (lane == 0) cnt[b] = base;
}

__global__ void k_scan(const int* __restrict__ cnt, int* __restrict__ roff, int Bn) {
    __shared__ int sums[1024];
    int tid = threadIdx.x;
    int per = Bn / 1024;
    int loc[8];
    int s = 0;
    for (int i = 0; i < per; ++i) { loc[i] = s; s += cnt[tid * per + i]; }
    sums[tid] = s;
    __syncthreads();
    for (int off = 1; off < 1024; off <<= 1) {
        int t = sums[tid];
        int v = (tid >= off) ? sums[tid - off] : 0;
        __syncthreads();
        sums[tid] = t + v;
        __syncthreads();
    }
    int excl = sums[tid] - s;
    for (int i = 0; i < per; ++i) roff[tid * per + i] = excl + loc[i];
}

// packid[r] = (b<<16)|n for masked samples; zero alpha for unmasked.
__global__ void k_packid(const void* __restrict__ maskp, const int* __restrict__ wsTot,
                         int P, const int* __restrict__ roff, unsigned* __restrict__ packid,
                         float* __restrict__ out_alpha, int N) {
    int b = blockIdx.x;
    int lane = threadIdx.x;
    int fl = (wsTot[0] == P);
    const unsigned char* m8 = (const unsigned char*)maskp;
    const int* m32 = (const int*)maskp;
    int base = roff[b];
    for (int t = 0; t < N / 64; ++t) {
        int n = t * 64 + lane;
        int mv = fl ? (int)m8[(size_t)b * N + n] : m32[(size_t)b * N + n];
        bool m = (mv != 0);
        unsigned long long bal = __ballot(m);
        int rank = __popcll(bal & ((1ull << lane) - 1ull));
        if (m) packid[base + rank] = ((unsigned)b << 16) | (unsigned)n;
        else   out_alpha[(size_t)b * N + n] = 0.0f;
        base += __popcll(bal);
    }
}

// hpe[b][row] = b1[row] + sum_j W1[row][28+j]*pe_b[j]; block 0 also fills W1bf.
__global__ __launch_bounds__(256) void k_hpe(
    const float* __restrict__ rays_d, const float* __restrict__ W1,
    const float* __restrict__ b1, short* __restrict__ W1bf,
    float* __restrict__ hpe, int Bn)
{
    __shared__ __align__(16) float w1pe[WIDTH * PEST];   // 28 KB
    __shared__ __align__(16) float pe_s[4][PEST];

    int tid = threadIdx.x;
    if (blockIdx.x == 0) {
        for (int t = tid; t < WIDTH * 32; t += 256) {
            int n = t / 32, k = t - n * 32;
            W1bf[t] = (k < DATA_DIM) ? f2bf(W1[n * IN_DIM + k]) : (short)0;
        }
    }
    for (int t = tid; t < WIDTH * PEST; t += 256) {
        int row = t / PEST, j = t - row * PEST;
        w1pe[t] = (j < 54) ? W1[row * IN_DIM + DATA_DIM + j] : 0.0f;
    }
    int wid = tid >> 6, lane = tid & 63;
    if (lane >= 54 && lane < PEST) pe_s[wid][lane] = 0.0f;
    __syncthreads();

    int raysPer = (Bn + gridDim.x - 1) / gridDim.x;
    for (int it = 0; it < raysPer; it += 4) {
        int b = blockIdx.x * raysPer + it + wid;
        if (b >= Bn) break;
        float dx = rays_d[b * 3 + 0], dy = rays_d[b * 3 + 1], dz = rays_d[b * 3 + 2];
        int idx = (lane < 54) ? lane : 0;
        int fb = idx / 6, t5 = idx - fb * 6;
        int ax = (t5 < 3) ? t5 : (t5 - 3);
        float dv = (ax == 0) ? dx : ((ax == 1) ? dy : dz);
        float ang = dv * (float)(1 << fb);
        float pev = (t5 < 3) ? sinf(ang) : cosf(ang);
        if (lane < 54) pe_s[wid][lane] = pev;

        #pragma unroll
        for (int rr = 0; rr < 2; ++rr) {
            int row = lane + 64 * rr;
            f32x4 s = {0.f, 0.f, 0.f, 0.f};
            #pragma unroll
            for (int j = 0; j < PEST; j += 4) {
                f32x4 wv = *reinterpret_cast<const f32x4*>(&w1pe[row * PEST + j]);
                f32x4 pv = *reinterpret_cast<const f32x4*>(&pe_s[wid][j]);
                s += wv * pv;
            }
            hpe[(size_t)b * WIDTH + row] = b1[row] + (s[0] + s[1]) + (s[2] + s[3]);
        }
    }
}

// ===== Phase 1: MLP over packed samples (R15 structure: flat batches, 1/wave).
// (256,4) occupancy push with register relief: w2f moved to LDS (-16 arch regs,
// R11's spill lesson); W1 fragments stay global (L1-hot) to keep LDS <= 40KB
// for 4 blocks/CU. Spill guard: WRITE_SIZE ~8MB.
__global__ __launch_bounds__(256, 4) void k_mlp(
    const float* __restrict__ data, const short* __restrict__ W1bf,
    const float* __restrict__ W2, const float* __restrict__ hpe,
    const unsigned* __restrict__ packid, uint2* __restrict__ preact, int P)
{
    int tid = threadIdx.x;
    int wid = tid >> 6;
    int lane = tid & 63;
    int g = lane >> 4, c = lane & 15;

    // XCD-aware bijective swizzle (T1, m204)
    int nwg = gridDim.x;
    int bid = blockIdx.x;
    if (nwg >= 8) {
        int q = nwg / 8, r = nwg % 8;
        int xcd = bid % 8, off = bid / 8;
        bid = (xcd < r ? xcd * (q + 1) : r * (q + 1) + (xcd - r) * q) + off;
    }
    int q0 = bid * 256 + wid * 64;

    __shared__ __align__(16) short stageH[4][64 * HST2];  // 36.9 KB
    __shared__ __align__(16) short w2s[5 * WIDTH];        // 1.25 KB (row 4 = zeros)

    // Stage W2 (4x128 bf16 + zero row) into LDS once per block.
    for (int t = tid; t < 5 * WIDTH; t += 256) {
        int r = t >> 7, k = t & 127;
        w2s[t] = (r < 4) ? f2bf(W2[r * WIDTH + k]) : (short)0;
    }

    short* hb = &stageH[wid][0];
    size_t maxoff = (size_t)P * 112 - 16;

    // coalesced stage: this wave's 64 data rows (7168 B)
    #pragma unroll
    for (int ci = 0; ci < 7; ++ci) {
        size_t off = (size_t)q0 * 112 + (size_t)ci * 1024 + (size_t)lane * 16;
        if (off > maxoff) off = maxoff;
        gload_lds16((const char*)data + off, (char*)hb + ci * 1024);
    }

    // packid loads (coalesced; overlap with staging)
    unsigned bs[4];
    #pragma unroll
    for (int mb = 0; mb < 4; ++mb) {
        int s = q0 + 16 * mb + c;
        s = (s < P) ? s : (P - 1);
        bs[mb] = packid[s] >> 16;
    }

    __syncthreads();   // w2s visible; also covers vmcnt? no — explicit drain:
    asm volatile("s_waitcnt vmcnt(0)" ::: "memory");

    // X B-fragments from LDS
    const float* hbf = reinterpret_cast<const float*>(hb);
    s16x8 a0[4];
    #pragma unroll
    for (int mb = 0; mb < 4; ++mb) {
        int row = 16 * mb + c;
        unsigned u0, u1, u2, u3;
        if (g < 3) {
            f32x4 lo = *reinterpret_cast<const f32x4*>(hbf + row * 28 + 8 * g);
            f32x4 hi = *reinterpret_cast<const f32x4*>(hbf + row * 28 + 8 * g + 4);
            u0 = pk2(lo[0], lo[1]); u1 = pk2(lo[2], lo[3]);
            u2 = pk2(hi[0], hi[1]); u3 = pk2(hi[2], hi[3]);
        } else {
            f32x4 lo = *reinterpret_cast<const f32x4*>(hbf + row * 28 + 24);
            u0 = pk2(lo[0], lo[1]); u1 = pk2(lo[2], lo[3]);
            u2 = 0; u3 = 0;
        }
        uint4 uu; uu.x = u0; uu.y = u1; uu.z = u2; uu.w = u3;
        a0[mb] = __builtin_bit_cast(s16x8, uu);
    }

    const s16x8* W1v = reinterpret_cast<const s16x8*>(W1bf);
    int w2row = (c < 4) ? c : 4;
    f32x4 D[4];
    #pragma unroll
    for (int t = 0; t < 4; ++t) D[t] = (f32x4){0.f, 0.f, 0.f, 0.f};

    #pragma unroll
    for (int ms = 0; ms < 2; ++ms) {
        #pragma unroll
        for (int hh = 0; hh < 4; ++hh) {
            int nt = 4 * ms + hh;
            s16x8 Bk0 = W1v[(16 * nt + c) * 4 + g];   // 8KB table, L1-resident

            f32x4 C0 = {0.f,0.f,0.f,0.f}, C1 = C0, C2 = C0, C3 = C0;
            C0 = __builtin_amdgcn_mfma_f32_16x16x32_bf16(Bk0, a0[0], C0, 0, 0, 0);
            C1 = __builtin_amdgcn_mfma_f32_16x16x32_bf16(Bk0, a0[1], C1, 0, 0, 0);
            C2 = __builtin_amdgcn_mfma_f32_16x16x32_bf16(Bk0, a0[2], C2, 0, 0, 0);
            C3 = __builtin_amdgcn_mfma_f32_16x16x32_bf16(Bk0, a0[3], C3, 0, 0, 0);

            f32x4 Cm[4] = {C0, C1, C2, C3};
            #pragma unroll
            for (int mb = 0; mb < 4; ++mb) {
                f32x4 hv = *reinterpret_cast<const f32x4*>(
                    hpe + (size_t)bs[mb] * WIDTH + 16 * nt + 4 * g);
                uint2 w;
                w.x = pk2(fmaxf(Cm[mb][0] + hv[0], 0.f), fmaxf(Cm[mb][1] + hv[1], 0.f));
                w.y = pk2(fmaxf(Cm[mb][2] + hv[2], 0.f), fmaxf(Cm[mb][3] + hv[3], 0.f));
                *reinterpret_cast<uint2*>(&hb[(16 * mb + c) * HST2 + 16 * hh + 4 * g]) = w;
            }
        }
        #pragma unroll
        for (int ks2 = 0; ks2 < 2; ++ks2) {
            s16x8 w2f = *reinterpret_cast<const s16x8*>(
                &w2s[w2row * WIDTH + 32 * (2 * ms + ks2) + 8 * g]);
            #pragma unroll
            for (int t = 0; t < 4; ++t) {
                s16x8 Bf = *reinterpret_cast<const s16x8*>(
                    &hb[(16 * t + c) * HST2 + 32 * ks2 + 8 * g]);
                D[t] = __builtin_amdgcn_mfma_f32_16x16x32_bf16(w2f, Bf, D[t], 0, 0, 0);
            }
        }
    }

    // outputs 0..3 live on g==0 lanes: lane c holds sample q0+16t+c
    if (g == 0) {
        #pragma unroll
        for (int t = 0; t < 4; ++t) {
            int s = q0 + 16 * t + c;
            if (s < P) {
                uint2 w;
                w.x = pk2(D[t][0], D[t][1]);
                w.y = pk2(D[t][2], D[t][3]);
                preact[s] = w;
            }
        }
    }
}

// ===== Phase 2: per-ray composite (wave per ray) — R15 proven version =====
__global__ __launch_bounds__(256) void k_comp(
    const float* __restrict__ rays_d, const float* __restrict__ intrs,
    const uint2* __restrict__ preact, const unsigned* __restrict__ packid,
    const int* __restrict__ cnt, const int* __restrict__ roff,
    const float* __restrict__ b2, float* __restrict__ out, int Bn, int N)
{
    int wid = threadIdx.x >> 6;
    int lane = threadIdx.x & 63;
    int b = blockIdx.x * 4 + wid;

    float* out_comp = out;
    float* out_alpha = out + (size_t)Bn * 3;

    int count = cnt[b];
    int poff = roff[b];

    float dx = rays_d[b * 3 + 0], dy = rays_d[b * 3 + 1], dz = rays_d[b * 3 + 2];
    float nrm = sqrtf(dx * dx + dy * dy + dz * dz);
    f32x4 b2v = *reinterpret_cast<const f32x4*>(b2);

    float T = 1.0f;
    float aR = 0.f, aG = 0.f, aB = 0.f, aA = 0.f;

    for (int r0 = 0; r0 < count; r0 += 64) {
        int r = r0 + lane;
        bool act = (r < count);
        int ri = poff + (act ? r : 0);
        uint2 pv = preact[ri];
        unsigned pos = packid[ri];
        int n = (int)(pos & 0xffffu);

        float p0 = bf2f(pv.x & 0xffffu) + b2v[0];
        float p1 = bf2f(pv.x >> 16)     + b2v[1];
        float p2 = bf2f(pv.y & 0xffffu) + b2v[2];
        float p3 = bf2f(pv.y >> 16)     + b2v[3];

        float density = fmaxf(p0, 0.0f);
        float dist = (intrs[(size_t)b * (N + 1) + n + 1] - intrs[(size_t)b * (N + 1) + n]) * nrm;
        float alpha = act ? (1.0f - expf(-density * dist)) : 0.0f;

        float fct = 1.0f - alpha + 1e-10f;
        float scan = fct;
        #pragma unroll
        for (int d = 1; d < 64; d <<= 1) {
            float o = __shfl_up(scan, d, 64);
            if (lane >= d) scan *= o;
        }
        float tot  = __shfl(scan, 63, 64);
        float excl = __shfl_up(scan, 1, 64);
        if (lane == 0) excl = 1.0f;

        float cum  = T * excl;
        float absl = alpha * cum;
        float sR = 1.0f / (1.0f + expf(-p1));
        float sG = 1.0f / (1.0f + expf(-p2));
        float sB = 1.0f / (1.0f + expf(-p3));
        aR = fmaf(absl, sR, aR);
        aG = fmaf(absl, sG, aG);
        aB = fmaf(absl, sB, aB);
        aA += absl;
        T *= tot;

        if (act) out_alpha[(size_t)b * N + n] = alpha;
    }

    #pragma unroll
    for (int d = 32; d > 0; d >>= 1) {
        aR += __shfl_down(aR, d, 64);
        aG += __shfl_down(aG, d, 64);
        aB += __shfl_down(aB, d, 64);
        aA += __shfl_down(aA, d, 64);
    }
    if (lane == 0) {
        out_comp[b * 3 + 0] = aR + (1.0f - aA);
        out_comp[b * 3 + 1] = aG + (1.0f - aA);
        out_comp[b * 3 + 2] = aB + (1.0f - aA);
    }
}

extern "C" void kernel_launch(void* const* d_in, const int* in_sizes, int n_in,
                              void* d_out, int out_size, void* d_ws, size_t ws_size,
                              hipStream_t stream) {
    const float* rays_d = (const float*)d_in[0];
    const float* intrs  = (const float*)d_in[1];
    const void*  maskp  = d_in[2];
    const float* data   = (const float*)d_in[3];
    const float* W1     = (const float*)d_in[4];
    const float* b1     = (const float*)d_in[5];
    const float* W2     = (const float*)d_in[6];
    const float* b2     = (const float*)d_in[7];
    float* out = (float*)d_out;

    int B = in_sizes[0] / 3;            // 8192
    int N = in_sizes[2] / B;            // 256
    int P = in_sizes[3] / DATA_DIM;     // packed sample count

    int* wsI    = (int*)d_ws;
    int* cnt    = wsI + 64;
    int* roff   = wsI + 64 + B;
    short* W1bf = (short*)(wsI + 64 + 2 * B);           // 8 KB
    float* hpe  = (float*)(W1bf + WIDTH * 32);          // B*128 f32 = 4 MB
    unsigned* packid = (unsigned*)(hpe + (size_t)B * WIDTH);  // P u32
    uint2* preact = (uint2*)(packid + ((P + 63) & ~63));      // P uint2

    float* out_alpha = out + (size_t)B * 3;

    hipMemsetAsync(d_ws, 0, 64, stream);
    int nwords = (B * N) / 4;
    k_count_bytes<<<256, 256, 0, stream>>>((const unsigned int*)maskp, nwords, wsI);
    k_cnt<<<B, 64, 0, stream>>>(maskp, wsI, P, cnt, N);
    k_scan<<<1, 1024, 0, stream>>>(cnt, roff, B);
    k_packid<<<B, 64, 0, stream>>>(maskp, wsI, P, roff, packid, out_alpha, N);
    k_hpe<<<256, 256, 0, stream>>>(rays_d, W1, b1, W1bf, hpe, B);
    k_mlp<<<(P + 255) / 256, 256, 0, stream>>>(data, W1bf, W2, hpe, packid, preact, P);
    k_comp<<<B / 4, 256, 0, stream>>>(rays_d, intrs, preact, packid, cnt, roff, b2,
                                      out, B, N);
}

// Round 19
// 96.499 us; speedup vs baseline: 1.3136x; 1.0935x over previous
//
#include <hip/hip_runtime.h>
#include <hip/hip_bf16.h>
#include <math.h>

#define FREQS 9
#define DATA_DIM 28
#define WIDTH 128
#define IN_DIM 82
#define HST2 72      // shorts per sample row in H stripe (144 B) -> ~2-way conflicts
#define PEST 56      // f32 per W1_pe row in LDS (padded 54->56)

typedef float f32x4 __attribute__((ext_vector_type(4)));
typedef short s16x8 __attribute__((ext_vector_type(8)));

__device__ __forceinline__ short f2bf(float f) {
    unsigned u = __builtin_bit_cast(unsigned, f);
    u += 0x7fffu + ((u >> 16) & 1u);
    return (short)(u >> 16);
}

// native RNE pack -> v_cvt_pk_bf16_f32 (m240: don't hand-roll)
__device__ __forceinline__ unsigned pk2(float a, float b) {
    float2 t; t.x = a; t.y = b;
    __hip_bfloat162 h = __float22bfloat162_rn(t);
    unsigned r;
    __builtin_memcpy(&r, &h, sizeof(r));
    return r;
}

__device__ __forceinline__ float bf2f(unsigned u16v) {
    unsigned u = u16v << 16;
    return __builtin_bit_cast(float, u);
}

// coalesced global->LDS (16B/lane, lds dest = uniform base + lane*16)
__device__ __forceinline__ void gload_lds16(const void* g, void* l) {
    __builtin_amdgcn_global_load_lds(
        (const __attribute__((address_space(1))) unsigned int*)g,
        (__attribute__((address_space(3))) unsigned int*)l, 16, 0, 0);
}

// Local mask-width detection (R19): int32 bool words are 0/1 (high bytes clear);
// byte-mask words have a high byte set w.p. 7/8. 64 words -> misdetect ~8^-64.
// Called with lane = threadIdx.x & 63; wave-uniform result.
__device__ __forceinline__ int detect_bytemask(const unsigned* __restrict__ mw, int lane) {
    unsigned w = mw[lane & 63];
    unsigned long long hi = __ballot((w & 0xFFFFFF00u) != 0);
    return hi != 0ull;
}

// ws: [64..64+B) cnt, [64+B..64+2B) roff, then W1bf 128*32 bf16 (8KB),
// hpe B*128 f32 (4MB), packid P u32, preact P uint2.
// R13 lesson: packed order is the reference's flatnonzero order (b-major,
// n-ascending exclusive scan). R17 lesson: flat sample-indexed batches beat
// ray-aligned (per-ray rounding +25% work, wave imbalance).

// per-ray masked count
__global__ void k_cnt(const void* __restrict__ maskp, int* __restrict__ cnt, int N) {
    int b = blockIdx.x;
    int lane = threadIdx.x;
    const unsigned char* m8 = (const unsigned char*)maskp;
    const int* m32 = (const int*)maskp;
    int fl = detect_bytemask((const unsigned*)maskp, lane);
    int base = 0;
    for (int t = 0; t < N / 64; ++t) {
        int n = t * 64 + lane;
        int mv = fl ? (int)m8[(size_t)b * N + n] : m32[(size_t)b * N + n];
        unsigned long long bal = __ballot(mv != 0);
        base += __popcll(bal);
    }
    if (lane == 0) cnt[b] = base;
}

__global__ void k_scan(const int* __restrict__ cnt, int* __restrict__ roff, int Bn) {
    __shared__ int sums[1024];
    int tid = threadIdx.x;
    int per = Bn / 1024;
    int loc[8];
    int s = 0;
    for (int i = 0; i < per; ++i) { loc[i] = s; s += cnt[tid * per + i]; }
    sums[tid] = s;
    __syncthreads();
    for (int off = 1; off < 1024; off <<= 1) {
        int t = sums[tid];
        int v = (tid >= off) ? sums[tid - off] : 0;
        __syncthreads();
        sums[tid] = t + v;
        __syncthreads();
    }
    int excl = sums[tid] - s;
    for (int i = 0; i < per; ++i) roff[tid * per + i] = excl + loc[i];
}

// packid[r] = (b<<16)|n for masked samples; zero alpha for unmasked.
__global__ void k_packid(const void* __restrict__ maskp, const int* __restrict__ roff,
                         unsigned* __restrict__ packid, float* __restrict__ out_alpha, int N) {
    int b = blockIdx.x;
    int lane = threadIdx.x;
    const unsigned char* m8 = (const unsigned char*)maskp;
    const int* m32 = (const int*)maskp;
    int fl = detect_bytemask((const unsigned*)maskp, lane);
    int base = roff[b];
    for (int t = 0; t < N / 64; ++t) {
        int n = t * 64 + lane;
        int mv = fl ? (int)m8[(size_t)b * N + n] : m32[(size_t)b * N + n];
        bool m = (mv != 0);
        unsigned long long bal = __ballot(m);
        int rank = __popcll(bal & ((1ull << lane) - 1ull));
        if (m) packid[base + rank] = ((unsigned)b << 16) | (unsigned)n;
        else   out_alpha[(size_t)b * N + n] = 0.0f;
        base += __popcll(bal);
    }
}

// hpe[b][row] = b1[row] + sum_j W1[row][28+j]*pe_b[j]; block 0 also fills W1bf.
__global__ __launch_bounds__(256) void k_hpe(
    const float* __restrict__ rays_d, const float* __restrict__ W1,
    const float* __restrict__ b1, short* __restrict__ W1bf,
    float* __restrict__ hpe, int Bn)
{
    __shared__ __align__(16) float w1pe[WIDTH * PEST];   // 28 KB
    __shared__ __align__(16) float pe_s[4][PEST];

    int tid = threadIdx.x;
    if (blockIdx.x == 0) {
        for (int t = tid; t < WIDTH * 32; t += 256) {
            int n = t / 32, k = t - n * 32;
            W1bf[t] = (k < DATA_DIM) ? f2bf(W1[n * IN_DIM + k]) : (short)0;
        }
    }
    for (int t = tid; t < WIDTH * PEST; t += 256) {
        int row = t / PEST, j = t - row * PEST;
        w1pe[t] = (j < 54) ? W1[row * IN_DIM + DATA_DIM + j] : 0.0f;
    }
    int wid = tid >> 6, lane = tid & 63;
    if (lane >= 54 && lane < PEST) pe_s[wid][lane] = 0.0f;
    __syncthreads();

    int raysPer = (Bn + gridDim.x - 1) / gridDim.x;
    for (int it = 0; it < raysPer; it += 4) {
        int b = blockIdx.x * raysPer + it + wid;
        if (b >= Bn) break;
        float dx = rays_d[b * 3 + 0], dy = rays_d[b * 3 + 1], dz = rays_d[b * 3 + 2];
        int idx = (lane < 54) ? lane : 0;
        int fb = idx / 6, t5 = idx - fb * 6;
        int ax = (t5 < 3) ? t5 : (t5 - 3);
        float dv = (ax == 0) ? dx : ((ax == 1) ? dy : dz);
        float ang = dv * (float)(1 << fb);
        float pev = (t5 < 3) ? sinf(ang) : cosf(ang);
        if (lane < 54) pe_s[wid][lane] = pev;

        #pragma unroll
        for (int rr = 0; rr < 2; ++rr) {
            int row = lane + 64 * rr;
            f32x4 s = {0.f, 0.f, 0.f, 0.f};
            #pragma unroll
            for (int j = 0; j < PEST; j += 4) {
                f32x4 wv = *reinterpret_cast<const f32x4*>(&w1pe[row * PEST + j]);
                f32x4 pv = *reinterpret_cast<const f32x4*>(&pe_s[wid][j]);
                s += wv * pv;
            }
            hpe[(size_t)b * WIDTH + row] = b1[row] + (s[0] + s[1]) + (s[2] + s[3]);
        }
    }
}

// ===== Phase 1: MLP over packed samples (R18 proven version, unchanged) =====
__global__ __launch_bounds__(256, 4) void k_mlp(
    const float* __restrict__ data, const short* __restrict__ W1bf,
    const float* __restrict__ W2, const float* __restrict__ hpe,
    const unsigned* __restrict__ packid, uint2* __restrict__ preact, int P)
{
    int tid = threadIdx.x;
    int wid = tid >> 6;
    int lane = tid & 63;
    int g = lane >> 4, c = lane & 15;

    // XCD-aware bijective swizzle (T1, m204)
    int nwg = gridDim.x;
    int bid = blockIdx.x;
    if (nwg >= 8) {
        int q = nwg / 8, r = nwg % 8;
        int xcd = bid % 8, off = bid / 8;
        bid = (xcd < r ? xcd * (q + 1) : r * (q + 1) + (xcd - r) * q) + off;
    }
    int q0 = bid * 256 + wid * 64;

    __shared__ __align__(16) short stageH[4][64 * HST2];  // 36.9 KB
    __shared__ __align__(16) short w2s[5 * WIDTH];        // 1.25 KB (row 4 = zeros)

    // Stage W2 (4x128 bf16 + zero row) into LDS once per block.
    for (int t = tid; t < 5 * WIDTH; t += 256) {
        int r = t >> 7, k = t & 127;
        w2s[t] = (r < 4) ? f2bf(W2[r * WIDTH + k]) : (short)0;
    }

    short* hb = &stageH[wid][0];
    size_t maxoff = (size_t)P * 112 - 16;

    // coalesced stage: this wave's 64 data rows (7168 B)
    #pragma unroll
    for (int ci = 0; ci < 7; ++ci) {
        size_t off = (size_t)q0 * 112 + (size_t)ci * 1024 + (size_t)lane * 16;
        if (off > maxoff) off = maxoff;
        gload_lds16((const char*)data + off, (char*)hb + ci * 1024);
    }

    // packid loads (coalesced; overlap with staging)
    unsigned bs[4];
    #pragma unroll
    for (int mb = 0; mb < 4; ++mb) {
        int s = q0 + 16 * mb + c;
        s = (s < P) ? s : (P - 1);
        bs[mb] = packid[s] >> 16;
    }

    __syncthreads();   // w2s visible
    asm volatile("s_waitcnt vmcnt(0)" ::: "memory");

    // X B-fragments from LDS
    const float* hbf = reinterpret_cast<const float*>(hb);
    s16x8 a0[4];
    #pragma unroll
    for (int mb = 0; mb < 4; ++mb) {
        int row = 16 * mb + c;
        unsigned u0, u1, u2, u3;
        if (g < 3) {
            f32x4 lo = *reinterpret_cast<const f32x4*>(hbf + row * 28 + 8 * g);
            f32x4 hi = *reinterpret_cast<const f32x4*>(hbf + row * 28 + 8 * g + 4);
            u0 = pk2(lo[0], lo[1]); u1 = pk2(lo[2], lo[3]);
            u2 = pk2(hi[0], hi[1]); u3 = pk2(hi[2], hi[3]);
        } else {
            f32x4 lo = *reinterpret_cast<const f32x4*>(hbf + row * 28 + 24);
            u0 = pk2(lo[0], lo[1]); u1 = pk2(lo[2], lo[3]);
            u2 = 0; u3 = 0;
        }
        uint4 uu; uu.x = u0; uu.y = u1; uu.z = u2; uu.w = u3;
        a0[mb] = __builtin_bit_cast(s16x8, uu);
    }

    const s16x8* W1v = reinterpret_cast<const s16x8*>(W1bf);
    int w2row = (c < 4) ? c : 4;
    f32x4 D[4];
    #pragma unroll
    for (int t = 0; t < 4; ++t) D[t] = (f32x4){0.f, 0.f, 0.f, 0.f};

    #pragma unroll
    for (int ms = 0; ms < 2; ++ms) {
        #pragma unroll
        for (int hh = 0; hh < 4; ++hh) {
            int nt = 4 * ms + hh;
            s16x8 Bk0 = W1v[(16 * nt + c) * 4 + g];   // 8KB table, L1-resident

            f32x4 C0 = {0.f,0.f,0.f,0.f}, C1 = C0, C2 = C0, C3 = C0;
            C0 = __builtin_amdgcn_mfma_f32_16x16x32_bf16(Bk0, a0[0], C0, 0, 0, 0);
            C1 = __builtin_amdgcn_mfma_f32_16x16x32_bf16(Bk0, a0[1], C1, 0, 0, 0);
            C2 = __builtin_amdgcn_mfma_f32_16x16x32_bf16(Bk0, a0[2], C2, 0, 0, 0);
            C3 = __builtin_amdgcn_mfma_f32_16x16x32_bf16(Bk0, a0[3], C3, 0, 0, 0);

            f32x4 Cm[4] = {C0, C1, C2, C3};
            #pragma unroll
            for (int mb = 0; mb < 4; ++mb) {
                f32x4 hv = *reinterpret_cast<const f32x4*>(
                    hpe + (size_t)bs[mb] * WIDTH + 16 * nt + 4 * g);
                uint2 w;
                w.x = pk2(fmaxf(Cm[mb][0] + hv[0], 0.f), fmaxf(Cm[mb][1] + hv[1], 0.f));
                w.y = pk2(fmaxf(Cm[mb][2] + hv[2], 0.f), fmaxf(Cm[mb][3] + hv[3], 0.f));
                *reinterpret_cast<uint2*>(&hb[(16 * mb + c) * HST2 + 16 * hh + 4 * g]) = w;
            }
        }
        #pragma unroll
        for (int ks2 = 0; ks2 < 2; ++ks2) {
            s16x8 w2f = *reinterpret_cast<const s16x8*>(
                &w2s[w2row * WIDTH + 32 * (2 * ms + ks2) + 8 * g]);
            #pragma unroll
            for (int t = 0; t < 4; ++t) {
                s16x8 Bf = *reinterpret_cast<const s16x8*>(
                    &hb[(16 * t + c) * HST2 + 32 * ks2 + 8 * g]);
                D[t] = __builtin_amdgcn_mfma_f32_16x16x32_bf16(w2f, Bf, D[t], 0, 0, 0);
            }
        }
    }

    // outputs 0..3 live on g==0 lanes: lane c holds sample q0+16t+c
    if (g == 0) {
        #pragma unroll
        for (int t = 0; t < 4; ++t) {
            int s = q0 + 16 * t + c;
            if (s < P) {
                uint2 w;
                w.x = pk2(D[t][0], D[t][1]);
                w.y = pk2(D[t][2], D[t][3]);
                preact[s] = w;
            }
        }
    }
}

// ===== Phase 2: per-ray composite (wave per ray) — unchanged =====
__global__ __launch_bounds__(256) void k_comp(
    const float* __restrict__ rays_d, const float* __restrict__ intrs,
    const uint2* __restrict__ preact, const unsigned* __restrict__ packid,
    const int* __restrict__ cnt, const int* __restrict__ roff,
    const float* __restrict__ b2, float* __restrict__ out, int Bn, int N)
{
    int wid = threadIdx.x >> 6;
    int lane = threadIdx.x & 63;
    int b = blockIdx.x * 4 + wid;

    float* out_comp = out;
    float* out_alpha = out + (size_t)Bn * 3;

    int count = cnt[b];
    int poff = roff[b];

    float dx = rays_d[b * 3 + 0], dy = rays_d[b * 3 + 1], dz = rays_d[b * 3 + 2];
    float nrm = sqrtf(dx * dx + dy * dy + dz * dz);
    f32x4 b2v = *reinterpret_cast<const f32x4*>(b2);

    float T = 1.0f;
    float aR = 0.f, aG = 0.f, aB = 0.f, aA = 0.f;

    for (int r0 = 0; r0 < count; r0 += 64) {
        int r = r0 + lane;
        bool act = (r < count);
        int ri = poff + (act ? r : 0);
        uint2 pv = preact[ri];
        unsigned pos = packid[ri];
        int n = (int)(pos & 0xffffu);

        float p0 = bf2f(pv.x & 0xffffu) + b2v[0];
        float p1 = bf2f(pv.x >> 16)     + b2v[1];
        float p2 = bf2f(pv.y & 0xffffu) + b2v[2];
        float p3 = bf2f(pv.y >> 16)     + b2v[3];

        float density = fmaxf(p0, 0.0f);
        float dist = (intrs[(size_t)b * (N + 1) + n + 1] - intrs[(size_t)b * (N + 1) + n]) * nrm;
        float alpha = act ? (1.0f - expf(-density * dist)) : 0.0f;

        float fct = 1.0f - alpha + 1e-10f;
        float scan = fct;
        #pragma unroll
        for (int d = 1; d < 64; d <<= 1) {
            float o = __shfl_up(scan, d, 64);
            if (lane >= d) scan *= o;
        }
        float tot  = __shfl(scan, 63, 64);
        float excl = __shfl_up(scan, 1, 64);
        if (lane == 0) excl = 1.0f;

        float cum  = T * excl;
        float absl = alpha * cum;
        float sR = 1.0f / (1.0f + expf(-p1));
        float sG = 1.0f / (1.0f + expf(-p2));
        float sB = 1.0f / (1.0f + expf(-p3));
        aR = fmaf(absl, sR, aR);
        aG = fmaf(absl, sG, aG);
        aB = fmaf(absl, sB, aB);
        aA += absl;
        T *= tot;

        if (act) out_alpha[(size_t)b * N + n] = alpha;
    }

    #pragma unroll
    for (int d = 32; d > 0; d >>= 1) {
        aR += __shfl_down(aR, d, 64);
        aG += __shfl_down(aG, d, 64);
        aB += __shfl_down(aB, d, 64);
        aA += __shfl_down(aA, d, 64);
    }
    if (lane == 0) {
        out_comp[b * 3 + 0] = aR + (1.0f - aA);
        out_comp[b * 3 + 1] = aG + (1.0f - aA);
        out_comp[b * 3 + 2] = aB + (1.0f - aA);
    }
}

extern "C" void kernel_launch(void* const* d_in, const int* in_sizes, int n_in,
                              void* d_out, int out_size, void* d_ws, size_t ws_size,
                              hipStream_t stream) {
    const float* rays_d = (const float*)d_in[0];
    const float* intrs  = (const float*)d_in[1];
    const void*  maskp  = d_in[2];
    const float* data   = (const float*)d_in[3];
    const float* W1     = (const float*)d_in[4];
    const float* b1     = (const float*)d_in[5];
    const float* W2     = (const float*)d_in[6];
    const float* b2     = (const float*)d_in[7];
    float* out = (float*)d_out;

    int B = in_sizes[0] / 3;            // 8192
    int N = in_sizes[2] / B;            // 256
    int P = in_sizes[3] / DATA_DIM;     // packed sample count

    int* wsI    = (int*)d_ws;
    int* cnt    = wsI + 64;
    int* roff   = wsI + 64 + B;
    short* W1bf = (short*)(wsI + 64 + 2 * B);           // 8 KB
    float* hpe  = (float*)(W1bf + WIDTH * 32);          // B*128 f32 = 4 MB
    unsigned* packid = (unsigned*)(hpe + (size_t)B * WIDTH);  // P u32
    uint2* preact = (uint2*)(packid + ((P + 63) & ~63));      // P uint2

    float* out_alpha = out + (size_t)B * 3;

    k_cnt<<<B, 64, 0, stream>>>(maskp, cnt, N);
    k_scan<<<1, 1024, 0, stream>>>(cnt, roff, B);
    k_packid<<<B, 64, 0, stream>>>(maskp, roff, packid, out_alpha, N);
    k_hpe<<<256, 256, 0, stream>>>(rays_d, W1, b1, W1bf, hpe, B);
    k_mlp<<<(P + 255) / 256, 256, 0, stream>>>(data, W1bf, W2, hpe, packid, preact, P);
    k_comp<<<B / 4, 256, 0, stream>>>(rays_d, intrs, preact, packid, cnt, roff, b2,
                                      out, B, N);
}

// Round 20
// 90.977 us; speedup vs baseline: 1.3934x; 1.0607x over previous
//
#include <hip/hip_runtime.h>
#include <hip/hip_bf16.h>
#include <math.h>

#define FREQS 9
#define DATA_DIM 28
#define WIDTH 128
#define IN_DIM 82
#define HST2 72      // shorts per sample row in H stripe (144 B) -> ~2-way conflicts
#define PEST 56      // f32 per W1_pe row in LDS (padded 54->56)

typedef float f32x4 __attribute__((ext_vector_type(4)));
typedef short s16x8 __attribute__((ext_vector_type(8)));

__device__ __forceinline__ short f2bf(float f) {
    unsigned u = __builtin_bit_cast(unsigned, f);
    u += 0x7fffu + ((u >> 16) & 1u);
    return (short)(u >> 16);
}

// native RNE pack -> v_cvt_pk_bf16_f32 (m240: don't hand-roll)
__device__ __forceinline__ unsigned pk2(float a, float b) {
    float2 t; t.x = a; t.y = b;
    __hip_bfloat162 h = __float22bfloat162_rn(t);
    unsigned r;
    __builtin_memcpy(&r, &h, sizeof(r));
    return r;
}

__device__ __forceinline__ float bf2f(unsigned u16v) {
    unsigned u = u16v << 16;
    return __builtin_bit_cast(float, u);
}

// coalesced global->LDS (16B/lane, lds dest = uniform base + lane*16)
__device__ __forceinline__ void gload_lds16(const void* g, void* l) {
    __builtin_amdgcn_global_load_lds(
        (const __attribute__((address_space(1))) unsigned int*)g,
        (__attribute__((address_space(3))) unsigned int*)l, 16, 0, 0);
}

// Local mask-width detection (R19-proven): int32 bool words are 0/1 (high bytes
// clear); byte-mask words have a high byte set w.p. 7/8. 64 words -> ~8^-64.
__device__ __forceinline__ int detect_bytemask(const unsigned* __restrict__ mw, int lane) {
    unsigned w = mw[lane & 63];
    unsigned long long hi = __ballot((w & 0xFFFFFF00u) != 0);
    return hi != 0ull;
}

// ws: [64..64+B) cnt, [64+B..64+2B) roff, then W1bf 128*32 bf16 (8KB),
// hpe B*128 f32 (4MB), packid P u32, preact P uint2.
// R13: packed order = reference flatnonzero order (b-major scan); no atomics.
// R17: flat sample-indexed batches beat ray-aligned.

// Fused prep: blocks 0..255 compute hpe (+W1bf in block 0); blocks 256.. count
// masked samples for 4 rays each (wave per ray).
__global__ __launch_bounds__(256) void k_prep(
    const float* __restrict__ rays_d, const float* __restrict__ W1,
    const float* __restrict__ b1, const void* __restrict__ maskp,
    short* __restrict__ W1bf, float* __restrict__ hpe,
    int* __restrict__ cnt, int Bn, int N)
{
    int tid = threadIdx.x;
    int wid = tid >> 6, lane = tid & 63;

    if (blockIdx.x >= 256) {
        // ---- cnt part: 4 rays per block ----
        int b = (blockIdx.x - 256) * 4 + wid;
        if (b >= Bn) return;
        const unsigned char* m8 = (const unsigned char*)maskp;
        const int* m32 = (const int*)maskp;
        int fl = detect_bytemask((const unsigned*)maskp, lane);
        int base = 0;
        for (int t = 0; t < N / 64; ++t) {
            int n = t * 64 + lane;
            int mv = fl ? (int)m8[(size_t)b * N + n] : m32[(size_t)b * N + n];
            unsigned long long bal = __ballot(mv != 0);
            base += __popcll(bal);
        }
        if (lane == 0) cnt[b] = base;
        return;
    }

    // ---- hpe part ----
    __shared__ __align__(16) float w1pe[WIDTH * PEST];   // 28 KB
    __shared__ __align__(16) float pe_s[4][PEST];

    if (blockIdx.x == 0) {
        for (int t = tid; t < WIDTH * 32; t += 256) {
            int n = t / 32, k = t - n * 32;
            W1bf[t] = (k < DATA_DIM) ? f2bf(W1[n * IN_DIM + k]) : (short)0;
        }
    }
    for (int t = tid; t < WIDTH * PEST; t += 256) {
        int row = t / PEST, j = t - row * PEST;
        w1pe[t] = (j < 54) ? W1[row * IN_DIM + DATA_DIM + j] : 0.0f;
    }
    if (lane >= 54 && lane < PEST) pe_s[wid][lane] = 0.0f;
    __syncthreads();

    int raysPer = (Bn + 255) / 256;
    for (int it = 0; it < raysPer; it += 4) {
        int b = blockIdx.x * raysPer + it + wid;
        if (b >= Bn) break;
        float dx = rays_d[b * 3 + 0], dy = rays_d[b * 3 + 1], dz = rays_d[b * 3 + 2];
        int idx = (lane < 54) ? lane : 0;
        int fb = idx / 6, t5 = idx - fb * 6;
        int ax = (t5 < 3) ? t5 : (t5 - 3);
        float dv = (ax == 0) ? dx : ((ax == 1) ? dy : dz);
        float ang = dv * (float)(1 << fb);
        float pev = (t5 < 3) ? sinf(ang) : cosf(ang);
        if (lane < 54) pe_s[wid][lane] = pev;

        #pragma unroll
        for (int rr = 0; rr < 2; ++rr) {
            int row = lane + 64 * rr;
            f32x4 s = {0.f, 0.f, 0.f, 0.f};
            #pragma unroll
            for (int j = 0; j < PEST; j += 4) {
                f32x4 wv = *reinterpret_cast<const f32x4*>(&w1pe[row * PEST + j]);
                f32x4 pv = *reinterpret_cast<const f32x4*>(&pe_s[wid][j]);
                s += wv * pv;
            }
            hpe[(size_t)b * WIDTH + row] = b1[row] + (s[0] + s[1]) + (s[2] + s[3]);
        }
    }
}

__global__ void k_scan(const int* __restrict__ cnt, int* __restrict__ roff, int Bn) {
    __shared__ int sums[1024];
    int tid = threadIdx.x;
    int per = Bn / 1024;
    int loc[8];
    int s = 0;
    for (int i = 0; i < per; ++i) { loc[i] = s; s += cnt[tid * per + i]; }
    sums[tid] = s;
    __syncthreads();
    for (int off = 1; off < 1024; off <<= 1) {
        int t = sums[tid];
        int v = (tid >= off) ? sums[tid - off] : 0;
        __syncthreads();
        sums[tid] = t + v;
        __syncthreads();
    }
    int excl = sums[tid] - s;
    for (int i = 0; i < per; ++i) roff[tid * per + i] = excl + loc[i];
}

// packid[r] = (b<<16)|n for masked samples; zero alpha for unmasked. 4 rays/block.
__global__ __launch_bounds__(256) void k_packid(
    const void* __restrict__ maskp, const int* __restrict__ roff,
    unsigned* __restrict__ packid, float* __restrict__ out_alpha, int N)
{
    int wid = threadIdx.x >> 6;
    int lane = threadIdx.x & 63;
    int b = blockIdx.x * 4 + wid;
    const unsigned char* m8 = (const unsigned char*)maskp;
    const int* m32 = (const int*)maskp;
    int fl = detect_bytemask((const unsigned*)maskp, lane);
    int base = roff[b];
    for (int t = 0; t < N / 64; ++t) {
        int n = t * 64 + lane;
        int mv = fl ? (int)m8[(size_t)b * N + n] : m32[(size_t)b * N + n];
        bool m = (mv != 0);
        unsigned long long bal = __ballot(m);
        int rank = __popcll(bal & ((1ull << lane) - 1ull));
        if (m) packid[base + rank] = ((unsigned)b << 16) | (unsigned)n;
        else   out_alpha[(size_t)b * N + n] = 0.0f;
        base += __popcll(bal);
    }
}

// ===== Phase 1: MLP over packed samples (R18 proven version, unchanged) =====
__global__ __launch_bounds__(256, 4) void k_mlp(
    const float* __restrict__ data, const short* __restrict__ W1bf,
    const float* __restrict__ W2, const float* __restrict__ hpe,
    const unsigned* __restrict__ packid, uint2* __restrict__ preact, int P)
{
    int tid = threadIdx.x;
    int wid = tid >> 6;
    int lane = tid & 63;
    int g = lane >> 4, c = lane & 15;

    // XCD-aware bijective swizzle (T1, m204)
    int nwg = gridDim.x;
    int bid = blockIdx.x;
    if (nwg >= 8) {
        int q = nwg / 8, r = nwg % 8;
        int xcd = bid % 8, off = bid / 8;
        bid = (xcd < r ? xcd * (q + 1) : r * (q + 1) + (xcd - r) * q) + off;
    }
    int q0 = bid * 256 + wid * 64;

    __shared__ __align__(16) short stageH[4][64 * HST2];  // 36.9 KB
    __shared__ __align__(16) short w2s[5 * WIDTH];        // 1.25 KB (row 4 = zeros)

    for (int t = tid; t < 5 * WIDTH; t += 256) {
        int r = t >> 7, k = t & 127;
        w2s[t] = (r < 4) ? f2bf(W2[r * WIDTH + k]) : (short)0;
    }

    short* hb = &stageH[wid][0];
    size_t maxoff = (size_t)P * 112 - 16;

    #pragma unroll
    for (int ci = 0; ci < 7; ++ci) {
        size_t off = (size_t)q0 * 112 + (size_t)ci * 1024 + (size_t)lane * 16;
        if (off > maxoff) off = maxoff;
        gload_lds16((const char*)data + off, (char*)hb + ci * 1024);
    }

    unsigned bs[4];
    #pragma unroll
    for (int mb = 0; mb < 4; ++mb) {
        int s = q0 + 16 * mb + c;
        s = (s < P) ? s : (P - 1);
        bs[mb] = packid[s] >> 16;
    }

    __syncthreads();   // w2s visible
    asm volatile("s_waitcnt vmcnt(0)" ::: "memory");

    const float* hbf = reinterpret_cast<const float*>(hb);
    s16x8 a0[4];
    #pragma unroll
    for (int mb = 0; mb < 4; ++mb) {
        int row = 16 * mb + c;
        unsigned u0, u1, u2, u3;
        if (g < 3) {
            f32x4 lo = *reinterpret_cast<const f32x4*>(hbf + row * 28 + 8 * g);
            f32x4 hi = *reinterpret_cast<const f32x4*>(hbf + row * 28 + 8 * g + 4);
            u0 = pk2(lo[0], lo[1]); u1 = pk2(lo[2], lo[3]);
            u2 = pk2(hi[0], hi[1]); u3 = pk2(hi[2], hi[3]);
        } else {
            f32x4 lo = *reinterpret_cast<const f32x4*>(hbf + row * 28 + 24);
            u0 = pk2(lo[0], lo[1]); u1 = pk2(lo[2], lo[3]);
            u2 = 0; u3 = 0;
        }
        uint4 uu; uu.x = u0; uu.y = u1; uu.z = u2; uu.w = u3;
        a0[mb] = __builtin_bit_cast(s16x8, uu);
    }

    const s16x8* W1v = reinterpret_cast<const s16x8*>(W1bf);
    int w2row = (c < 4) ? c : 4;
    f32x4 D[4];
    #pragma unroll
    for (int t = 0; t < 4; ++t) D[t] = (f32x4){0.f, 0.f, 0.f, 0.f};

    #pragma unroll
    for (int ms = 0; ms < 2; ++ms) {
        #pragma unroll
        for (int hh = 0; hh < 4; ++hh) {
            int nt = 4 * ms + hh;
            s16x8 Bk0 = W1v[(16 * nt + c) * 4 + g];   // 8KB table, L1-resident

            f32x4 C0 = {0.f,0.f,0.f,0.f}, C1 = C0, C2 = C0, C3 = C0;
            C0 = __builtin_amdgcn_mfma_f32_16x16x32_bf16(Bk0, a0[0], C0, 0, 0, 0);
            C1 = __builtin_amdgcn_mfma_f32_16x16x32_bf16(Bk0, a0[1], C1, 0, 0, 0);
            C2 = __builtin_amdgcn_mfma_f32_16x16x32_bf16(Bk0, a0[2], C2, 0, 0, 0);
            C3 = __builtin_amdgcn_mfma_f32_16x16x32_bf16(Bk0, a0[3], C3, 0, 0, 0);

            f32x4 Cm[4] = {C0, C1, C2, C3};
            #pragma unroll
            for (int mb = 0; mb < 4; ++mb) {
                f32x4 hv = *reinterpret_cast<const f32x4*>(
                    hpe + (size_t)bs[mb] * WIDTH + 16 * nt + 4 * g);
                uint2 w;
                w.x = pk2(fmaxf(Cm[mb][0] + hv[0], 0.f), fmaxf(Cm[mb][1] + hv[1], 0.f));
                w.y = pk2(fmaxf(Cm[mb][2] + hv[2], 0.f), fmaxf(Cm[mb][3] + hv[3], 0.f));
                *reinterpret_cast<uint2*>(&hb[(16 * mb + c) * HST2 + 16 * hh + 4 * g]) = w;
            }
        }
        #pragma unroll
        for (int ks2 = 0; ks2 < 2; ++ks2) {
            s16x8 w2f = *reinterpret_cast<const s16x8*>(
                &w2s[w2row * WIDTH + 32 * (2 * ms + ks2) + 8 * g]);
            #pragma unroll
            for (int t = 0; t < 4; ++t) {
                s16x8 Bf = *reinterpret_cast<const s16x8*>(
                    &hb[(16 * t + c) * HST2 + 32 * ks2 + 8 * g]);
                D[t] = __builtin_amdgcn_mfma_f32_16x16x32_bf16(w2f, Bf, D[t], 0, 0, 0);
            }
        }
    }

    if (g == 0) {
        #pragma unroll
        for (int t = 0; t < 4; ++t) {
            int s = q0 + 16 * t + c;
            if (s < P) {
                uint2 w;
                w.x = pk2(D[t][0], D[t][1]);
                w.y = pk2(D[t][2], D[t][3]);
                preact[s] = w;
            }
        }
    }
}

// ===== Phase 2: per-ray composite (wave per ray) — unchanged =====
__global__ __launch_bounds__(256) void k_comp(
    const float* __restrict__ rays_d, const float* __restrict__ intrs,
    const uint2* __restrict__ preact, const unsigned* __restrict__ packid,
    const int* __restrict__ cnt, const int* __restrict__ roff,
    const float* __restrict__ b2, float* __restrict__ out, int Bn, int N)
{
    int wid = threadIdx.x >> 6;
    int lane = threadIdx.x & 63;
    int b = blockIdx.x * 4 + wid;

    float* out_comp = out;
    float* out_alpha = out + (size_t)Bn * 3;

    int count = cnt[b];
    int poff = roff[b];

    float dx = rays_d[b * 3 + 0], dy = rays_d[b * 3 + 1], dz = rays_d[b * 3 + 2];
    float nrm = sqrtf(dx * dx + dy * dy + dz * dz);
    f32x4 b2v = *reinterpret_cast<const f32x4*>(b2);

    float T = 1.0f;
    float aR = 0.f, aG = 0.f, aB = 0.f, aA = 0.f;

    for (int r0 = 0; r0 < count; r0 += 64) {
        int r = r0 + lane;
        bool act = (r < count);
        int ri = poff + (act ? r : 0);
        uint2 pv = preact[ri];
        unsigned pos = packid[ri];
        int n = (int)(pos & 0xffffu);

        float p0 = bf2f(pv.x & 0xffffu) + b2v[0];
        float p1 = bf2f(pv.x >> 16)     + b2v[1];
        float p2 = bf2f(pv.y & 0xffffu) + b2v[2];
        float p3 = bf2f(pv.y >> 16)     + b2v[3];

        float density = fmaxf(p0, 0.0f);
        float dist = (intrs[(size_t)b * (N + 1) + n + 1] - intrs[(size_t)b * (N + 1) + n]) * nrm;
        float alpha = act ? (1.0f - expf(-density * dist)) : 0.0f;

        float fct = 1.0f - alpha + 1e-10f;
        float scan = fct;
        #pragma unroll
        for (int d = 1; d < 64; d <<= 1) {
            float o = __shfl_up(scan, d, 64);
            if (lane >= d) scan *= o;
        }
        float tot  = __shfl(scan, 63, 64);
        float excl = __shfl_up(scan, 1, 64);
        if (lane == 0) excl = 1.0f;

        float cum  = T * excl;
        float absl = alpha * cum;
        float sR = 1.0f / (1.0f + expf(-p1));
        float sG = 1.0f / (1.0f + expf(-p2));
        float sB = 1.0f / (1.0f + expf(-p3));
        aR = fmaf(absl, sR, aR);
        aG = fmaf(absl, sG, aG);
        aB = fmaf(absl, sB, aB);
        aA += absl;
        T *= tot;

        if (act) out_alpha[(size_t)b * N + n] = alpha;
    }

    #pragma unroll
    for (int d = 32; d > 0; d >>= 1) {
        aR += __shfl_down(aR, d, 64);
        aG += __shfl_down(aG, d, 64);
        aB += __shfl_down(aB, d, 64);
        aA += __shfl_down(aA, d, 64);
    }
    if (lane == 0) {
        out_comp[b * 3 + 0] = aR + (1.0f - aA);
        out_comp[b * 3 + 1] = aG + (1.0f - aA);
        out_comp[b * 3 + 2] = aB + (1.0f - aA);
    }
}

extern "C" void kernel_launch(void* const* d_in, const int* in_sizes, int n_in,
                              void* d_out, int out_size, void* d_ws, size_t ws_size,
                              hipStream_t stream) {
    const float* rays_d = (const float*)d_in[0];
    const float* intrs  = (const float*)d_in[1];
    const void*  maskp  = d_in[2];
    const float* data   = (const float*)d_in[3];
    const float* W1     = (const float*)d_in[4];
    const float* b1     = (const float*)d_in[5];
    const float* W2     = (const float*)d_in[6];
    const float* b2     = (const float*)d_in[7];
    float* out = (float*)d_out;

    int B = in_sizes[0] / 3;            // 8192
    int N = in_sizes[2] / B;            // 256
    int P = in_sizes[3] / DATA_DIM;     // packed sample count

    int* wsI    = (int*)d_ws;
    int* cnt    = wsI + 64;
    int* roff   = wsI + 64 + B;
    short* W1bf = (short*)(wsI + 64 + 2 * B);           // 8 KB
    float* hpe  = (float*)(W1bf + WIDTH * 32);          // B*128 f32 = 4 MB
    unsigned* packid = (unsigned*)(hpe + (size_t)B * WIDTH);  // P u32
    uint2* preact = (uint2*)(packid + ((P + 63) & ~63));      // P uint2

    float* out_alpha = out + (size_t)B * 3;

    k_prep<<<256 + B / 4, 256, 0, stream>>>(rays_d, W1, b1, maskp, W1bf, hpe, cnt, B, N);
    k_scan<<<1, 1024, 0, stream>>>(cnt, roff, B);
    k_packid<<<B / 4, 256, 0, stream>>>(maskp, roff, packid, out_alpha, N);
    k_mlp<<<(P + 255) / 256, 256, 0, stream>>>(data, W1bf, W2, hpe, packid, preact, P);
    k_comp<<<B / 4, 256, 0, stream>>>(rays_d, intrs, preact, packid, cnt, roff, b2,
                                      out, B, N);
}

// Round 21
// 88.929 us; speedup vs baseline: 1.4255x; 1.0230x over previous
//
#include <hip/hip_runtime.h>
#include <hip/hip_bf16.h>
#include <math.h>

#define FREQS 9
#define DATA_DIM 28
#define WIDTH 128
#define IN_DIM 82
#define HST2 72      // shorts per sample row in H stripe (144 B) -> ~2-way conflicts
#define PEST 56      // f32 per W1_pe row in LDS (padded 54->56)

typedef float f32x4 __attribute__((ext_vector_type(4)));
typedef short s16x8 __attribute__((ext_vector_type(8)));

__device__ __forceinline__ short f2bf(float f) {
    unsigned u = __builtin_bit_cast(unsigned, f);
    u += 0x7fffu + ((u >> 16) & 1u);
    return (short)(u >> 16);
}

// native RNE pack -> v_cvt_pk_bf16_f32 (m240: don't hand-roll)
__device__ __forceinline__ unsigned pk2(float a, float b) {
    float2 t; t.x = a; t.y = b;
    __hip_bfloat162 h = __float22bfloat162_rn(t);
    unsigned r;
    __builtin_memcpy(&r, &h, sizeof(r));
    return r;
}

__device__ __forceinline__ float bf2f(unsigned u16v) {
    unsigned u = u16v << 16;
    return __builtin_bit_cast(float, u);
}

// coalesced global->LDS (16B/lane, lds dest = uniform base + lane*16)
__device__ __forceinline__ void gload_lds16(const void* g, void* l) {
    __builtin_amdgcn_global_load_lds(
        (const __attribute__((address_space(1))) unsigned int*)g,
        (__attribute__((address_space(3))) unsigned int*)l, 16, 0, 0);
}

// Local mask-width detection (R19-proven): int32 bool words are 0/1 (high bytes
// clear); byte-mask words have a high byte set w.p. 7/8. 64 words -> ~8^-64.
__device__ __forceinline__ int detect_bytemask(const unsigned* __restrict__ mw, int lane) {
    unsigned w = mw[lane & 63];
    unsigned long long hi = __ballot((w & 0xFFFFFF00u) != 0);
    return hi != 0ull;
}

// ws: [64..64+B) cnt, [64+B..64+2B) roff, then W1bf 128*32 bf16 (8KB),
// W2bf 5*128 bf16 padded to 1024 shorts (2KB), hpe B*128 f32 (4MB),
// packid P u32, preact P uint2.
// R13: packed order = reference flatnonzero order (b-major scan); no atomics.
// R17: flat sample-indexed batches beat ray-aligned.

// Fused prep: blocks 0..255 compute hpe (+W1bf/W2bf in block 0); blocks 256..
// count masked samples for 4 rays each (wave per ray).
__global__ __launch_bounds__(256) void k_prep(
    const float* __restrict__ rays_d, const float* __restrict__ W1,
    const float* __restrict__ b1, const float* __restrict__ W2,
    const void* __restrict__ maskp,
    short* __restrict__ W1bf, short* __restrict__ W2bf, float* __restrict__ hpe,
    int* __restrict__ cnt, int Bn, int N)
{
    int tid = threadIdx.x;
    int wid = tid >> 6, lane = tid & 63;

    if (blockIdx.x >= 256) {
        // ---- cnt part: 4 rays per block ----
        int b = (blockIdx.x - 256) * 4 + wid;
        if (b >= Bn) return;
        const unsigned char* m8 = (const unsigned char*)maskp;
        const int* m32 = (const int*)maskp;
        int fl = detect_bytemask((const unsigned*)maskp, lane);
        int base = 0;
        for (int t = 0; t < N / 64; ++t) {
            int n = t * 64 + lane;
            int mv = fl ? (int)m8[(size_t)b * N + n] : m32[(size_t)b * N + n];
            unsigned long long bal = __ballot(mv != 0);
            base += __popcll(bal);
        }
        if (lane == 0) cnt[b] = base;
        return;
    }

    // ---- hpe part ----
    __shared__ __align__(16) float w1pe[WIDTH * PEST];   // 28 KB
    __shared__ __align__(16) float pe_s[4][PEST];

    if (blockIdx.x == 0) {
        for (int t = tid; t < WIDTH * 32; t += 256) {
            int n = t / 32, k = t - n * 32;
            W1bf[t] = (k < DATA_DIM) ? f2bf(W1[n * IN_DIM + k]) : (short)0;
        }
        for (int t = tid; t < 5 * WIDTH; t += 256) {
            int r = t >> 7, k = t & 127;
            W2bf[t] = (r < 4) ? f2bf(W2[r * WIDTH + k]) : (short)0;
        }
    }
    for (int t = tid; t < WIDTH * PEST; t += 256) {
        int row = t / PEST, j = t - row * PEST;
        w1pe[t] = (j < 54) ? W1[row * IN_DIM + DATA_DIM + j] : 0.0f;
    }
    if (lane >= 54 && lane < PEST) pe_s[wid][lane] = 0.0f;
    __syncthreads();

    int raysPer = (Bn + 255) / 256;
    for (int it = 0; it < raysPer; it += 4) {
        int b = blockIdx.x * raysPer + it + wid;
        if (b >= Bn) break;
        float dx = rays_d[b * 3 + 0], dy = rays_d[b * 3 + 1], dz = rays_d[b * 3 + 2];
        int idx = (lane < 54) ? lane : 0;
        int fb = idx / 6, t5 = idx - fb * 6;
        int ax = (t5 < 3) ? t5 : (t5 - 3);
        float dv = (ax == 0) ? dx : ((ax == 1) ? dy : dz);
        float ang = dv * (float)(1 << fb);
        float pev = (t5 < 3) ? sinf(ang) : cosf(ang);
        if (lane < 54) pe_s[wid][lane] = pev;

        #pragma unroll
        for (int rr = 0; rr < 2; ++rr) {
            int row = lane + 64 * rr;
            f32x4 s = {0.f, 0.f, 0.f, 0.f};
            #pragma unroll
            for (int j = 0; j < PEST; j += 4) {
                f32x4 wv = *reinterpret_cast<const f32x4*>(&w1pe[row * PEST + j]);
                f32x4 pv = *reinterpret_cast<const f32x4*>(&pe_s[wid][j]);
                s += wv * pv;
            }
            hpe[(size_t)b * WIDTH + row] = b1[row] + (s[0] + s[1]) + (s[2] + s[3]);
        }
    }
}

// Shuffle-based scan: 1024 thr = 16 waves; 1 barrier total (was ~21).
__global__ void k_scan(const int* __restrict__ cnt, int* __restrict__ roff, int Bn) {
    __shared__ int wtot[16];
    int tid = threadIdx.x;
    int lane = tid & 63, w = tid >> 6;
    int per = Bn / 1024;
    int loc[8];
    int s = 0;
    for (int i = 0; i < per; ++i) { loc[i] = s; s += cnt[tid * per + i]; }
    int inc = s;
    #pragma unroll
    for (int d = 1; d < 64; d <<= 1) {
        int o = __shfl_up(inc, d, 64);
        if (lane >= d) inc += o;
    }
    if (lane == 63) wtot[w] = inc;
    __syncthreads();
    int woff = 0;
    for (int j = 0; j < w; ++j) woff += wtot[j];   // broadcast LDS reads
    int excl = woff + inc - s;
    for (int i = 0; i < per; ++i) roff[tid * per + i] = excl + loc[i];
}

// packid[r] = (b<<16)|n for masked samples; zero alpha for unmasked. 4 rays/block.
__global__ __launch_bounds__(256) void k_packid(
    const void* __restrict__ maskp, const int* __restrict__ roff,
    unsigned* __restrict__ packid, float* __restrict__ out_alpha, int N)
{
    int wid = threadIdx.x >> 6;
    int lane = threadIdx.x & 63;
    int b = blockIdx.x * 4 + wid;
    const unsigned char* m8 = (const unsigned char*)maskp;
    const int* m32 = (const int*)maskp;
    int fl = detect_bytemask((const unsigned*)maskp, lane);
    int base = roff[b];
    for (int t = 0; t < N / 64; ++t) {
        int n = t * 64 + lane;
        int mv = fl ? (int)m8[(size_t)b * N + n] : m32[(size_t)b * N + n];
        bool m = (mv != 0);
        unsigned long long bal = __ballot(m);
        int rank = __popcll(bal & ((1ull << lane) - 1ull));
        if (m) packid[base + rank] = ((unsigned)b << 16) | (unsigned)n;
        else   out_alpha[(size_t)b * N + n] = 0.0f;
        base += __popcll(bal);
    }
}

// ===== Phase 1: MLP over packed samples. Barrier-free: W2 from global bf16
// table (L1 broadcast), per-wave-private LDS slices, no __syncthreads. =====
__global__ __launch_bounds__(256, 4) void k_mlp(
    const float* __restrict__ data, const short* __restrict__ W1bf,
    const short* __restrict__ W2bf, const float* __restrict__ hpe,
    const unsigned* __restrict__ packid, uint2* __restrict__ preact, int P)
{
    int tid = threadIdx.x;
    int wid = tid >> 6;
    int lane = tid & 63;
    int g = lane >> 4, c = lane & 15;

    // XCD-aware bijective swizzle (T1, m204)
    int nwg = gridDim.x;
    int bid = blockIdx.x;
    if (nwg >= 8) {
        int q = nwg / 8, r = nwg % 8;
        int xcd = bid % 8, off = bid / 8;
        bid = (xcd < r ? xcd * (q + 1) : r * (q + 1) + (xcd - r) * q) + off;
    }
    int q0 = bid * 256 + wid * 64;

    __shared__ __align__(16) short stageH[4][64 * HST2];  // 36.9 KB

    short* hb = &stageH[wid][0];
    size_t maxoff = (size_t)P * 112 - 16;

    #pragma unroll
    for (int ci = 0; ci < 7; ++ci) {
        size_t off = (size_t)q0 * 112 + (size_t)ci * 1024 + (size_t)lane * 16;
        if (off > maxoff) off = maxoff;
        gload_lds16((const char*)data + off, (char*)hb + ci * 1024);
    }

    unsigned bs[4];
    #pragma unroll
    for (int mb = 0; mb < 4; ++mb) {
        int s = q0 + 16 * mb + c;
        s = (s < P) ? s : (P - 1);
        bs[mb] = packid[s] >> 16;
    }

    asm volatile("s_waitcnt vmcnt(0)" ::: "memory");   // staged data + bs ready

    const float* hbf = reinterpret_cast<const float*>(hb);
    s16x8 a0[4];
    #pragma unroll
    for (int mb = 0; mb < 4; ++mb) {
        int row = 16 * mb + c;
        unsigned u0, u1, u2, u3;
        if (g < 3) {
            f32x4 lo = *reinterpret_cast<const f32x4*>(hbf + row * 28 + 8 * g);
            f32x4 hi = *reinterpret_cast<const f32x4*>(hbf + row * 28 + 8 * g + 4);
            u0 = pk2(lo[0], lo[1]); u1 = pk2(lo[2], lo[3]);
            u2 = pk2(hi[0], hi[1]); u3 = pk2(hi[2], hi[3]);
        } else {
            f32x4 lo = *reinterpret_cast<const f32x4*>(hbf + row * 28 + 24);
            u0 = pk2(lo[0], lo[1]); u1 = pk2(lo[2], lo[3]);
            u2 = 0; u3 = 0;
        }
        uint4 uu; uu.x = u0; uu.y = u1; uu.z = u2; uu.w = u3;
        a0[mb] = __builtin_bit_cast(s16x8, uu);
    }

    const s16x8* W1v = reinterpret_cast<const s16x8*>(W1bf);
    int w2row = (c < 4) ? c : 4;
    f32x4 D[4];
    #pragma unroll
    for (int t = 0; t < 4; ++t) D[t] = (f32x4){0.f, 0.f, 0.f, 0.f};

    #pragma unroll
    for (int ms = 0; ms < 2; ++ms) {
        #pragma unroll
        for (int hh = 0; hh < 4; ++hh) {
            int nt = 4 * ms + hh;
            s16x8 Bk0 = W1v[(16 * nt + c) * 4 + g];   // 8KB table, L1-resident

            f32x4 C0 = {0.f,0.f,0.f,0.f}, C1 = C0, C2 = C0, C3 = C0;
            C0 = __builtin_amdgcn_mfma_f32_16x16x32_bf16(Bk0, a0[0], C0, 0, 0, 0);
            C1 = __builtin_amdgcn_mfma_f32_16x16x32_bf16(Bk0, a0[1], C1, 0, 0, 0);
            C2 = __builtin_amdgcn_mfma_f32_16x16x32_bf16(Bk0, a0[2], C2, 0, 0, 0);
            C3 = __builtin_amdgcn_mfma_f32_16x16x32_bf16(Bk0, a0[3], C3, 0, 0, 0);

            f32x4 Cm[4] = {C0, C1, C2, C3};
            #pragma unroll
            for (int mb = 0; mb < 4; ++mb) {
                f32x4 hv = *reinterpret_cast<const f32x4*>(
                    hpe + (size_t)bs[mb] * WIDTH + 16 * nt + 4 * g);
                uint2 w;
                w.x = pk2(fmaxf(Cm[mb][0] + hv[0], 0.f), fmaxf(Cm[mb][1] + hv[1], 0.f));
                w.y = pk2(fmaxf(Cm[mb][2] + hv[2], 0.f), fmaxf(Cm[mb][3] + hv[3], 0.f));
                *reinterpret_cast<uint2*>(&hb[(16 * mb + c) * HST2 + 16 * hh + 4 * g]) = w;
            }
        }
        #pragma unroll
        for (int ks2 = 0; ks2 < 2; ++ks2) {
            s16x8 w2f = *reinterpret_cast<const s16x8*>(
                W2bf + w2row * WIDTH + 32 * (2 * ms + ks2) + 8 * g);   // L1 broadcast
            #pragma unroll
            for (int t = 0; t < 4; ++t) {
                s16x8 Bf = *reinterpret_cast<const s16x8*>(
                    &hb[(16 * t + c) * HST2 + 32 * ks2 + 8 * g]);
                D[t] = __builtin_amdgcn_mfma_f32_16x16x32_bf16(w2f, Bf, D[t], 0, 0, 0);
            }
        }
    }

    if (g == 0) {
        #pragma unroll
        for (int t = 0; t < 4; ++t) {
            int s = q0 + 16 * t + c;
            if (s < P) {
                uint2 w;
                w.x = pk2(D[t][0], D[t][1]);
                w.y = pk2(D[t][2], D[t][3]);
                preact[s] = w;
            }
        }
    }
}

// ===== Phase 2: per-ray composite (wave per ray) — unchanged =====
__global__ __launch_bounds__(256) void k_comp(
    const float* __restrict__ rays_d, const float* __restrict__ intrs,
    const uint2* __restrict__ preact, const unsigned* __restrict__ packid,
    const int* __restrict__ cnt, const int* __restrict__ roff,
    const float* __restrict__ b2, float* __restrict__ out, int Bn, int N)
{
    int wid = threadIdx.x >> 6;
    int lane = threadIdx.x & 63;
    int b = blockIdx.x * 4 + wid;

    float* out_comp = out;
    float* out_alpha = out + (size_t)Bn * 3;

    int count = cnt[b];
    int poff = roff[b];

    float dx = rays_d[b * 3 + 0], dy = rays_d[b * 3 + 1], dz = rays_d[b * 3 + 2];
    float nrm = sqrtf(dx * dx + dy * dy + dz * dz);
    f32x4 b2v = *reinterpret_cast<const f32x4*>(b2);

    float T = 1.0f;
    float aR = 0.f, aG = 0.f, aB = 0.f, aA = 0.f;

    for (int r0 = 0; r0 < count; r0 += 64) {
        int r = r0 + lane;
        bool act = (r < count);
        int ri = poff + (act ? r : 0);
        uint2 pv = preact[ri];
        unsigned pos = packid[ri];
        int n = (int)(pos & 0xffffu);

        float p0 = bf2f(pv.x & 0xffffu) + b2v[0];
        float p1 = bf2f(pv.x >> 16)     + b2v[1];
        float p2 = bf2f(pv.y & 0xffffu) + b2v[2];
        float p3 = bf2f(pv.y >> 16)     + b2v[3];

        float density = fmaxf(p0, 0.0f);
        float dist = (intrs[(size_t)b * (N + 1) + n + 1] - intrs[(size_t)b * (N + 1) + n]) * nrm;
        float alpha = act ? (1.0f - expf(-density * dist)) : 0.0f;

        float fct = 1.0f - alpha + 1e-10f;
        float scan = fct;
        #pragma unroll
        for (int d = 1; d < 64; d <<= 1) {
            float o = __shfl_up(scan, d, 64);
            if (lane >= d) scan *= o;
        }
        float tot  = __shfl(scan, 63, 64);
        float excl = __shfl_up(scan, 1, 64);
        if (lane == 0) excl = 1.0f;

        float cum  = T * excl;
        float absl = alpha * cum;
        float sR = 1.0f / (1.0f + expf(-p1));
        float sG = 1.0f / (1.0f + expf(-p2));
        float sB = 1.0f / (1.0f + expf(-p3));
        aR = fmaf(absl, sR, aR);
        aG = fmaf(absl, sG, aG);
        aB = fmaf(absl, sB, aB);
        aA += absl;
        T *= tot;

        if (act) out_alpha[(size_t)b * N + n] = alpha;
    }

    #pragma unroll
    for (int d = 32; d > 0; d >>= 1) {
        aR += __shfl_down(aR, d, 64);
        aG += __shfl_down(aG, d, 64);
        aB += __shfl_down(aB, d, 64);
        aA += __shfl_down(aA, d, 64);
    }
    if (lane == 0) {
        out_comp[b * 3 + 0] = aR + (1.0f - aA);
        out_comp[b * 3 + 1] = aG + (1.0f - aA);
        out_comp[b * 3 + 2] = aB + (1.0f - aA);
    }
}

extern "C" void kernel_launch(void* const* d_in, const int* in_sizes, int n_in,
                              void* d_out, int out_size, void* d_ws, size_t ws_size,
                              hipStream_t stream) {
    const float* rays_d = (const float*)d_in[0];
    const float* intrs  = (const float*)d_in[1];
    const void*  maskp  = d_in[2];
    const float* data   = (const float*)d_in[3];
    const float* W1     = (const float*)d_in[4];
    const float* b1     = (const float*)d_in[5];
    const float* W2     = (const float*)d_in[6];
    const float* b2     = (const float*)d_in[7];
    float* out = (float*)d_out;

    int B = in_sizes[0] / 3;            // 8192
    int N = in_sizes[2] / B;            // 256
    int P = in_sizes[3] / DATA_DIM;     // packed sample count

    int* wsI    = (int*)d_ws;
    int* cnt    = wsI + 64;
    int* roff   = wsI + 64 + B;
    short* W1bf = (short*)(wsI + 64 + 2 * B);           // 8 KB
    short* W2bf = W1bf + WIDTH * 32;                    // 2 KB (1024 shorts)
    float* hpe  = (float*)(W2bf + 1024);                // B*128 f32 = 4 MB
    unsigned* packid = (unsigned*)(hpe + (size_t)B * WIDTH);  // P u32
    uint2* preact = (uint2*)(packid + ((P + 63) & ~63));      // P uint2

    float* out_alpha = out + (size_t)B * 3;

    k_prep<<<256 + B / 4, 256, 0, stream>>>(rays_d, W1, b1, W2, maskp,
                                            W1bf, W2bf, hpe, cnt, B, N);
    k_scan<<<1, 1024, 0, stream>>>(cnt, roff, B);
    k_packid<<<B / 4, 256, 0, stream>>>(maskp, roff, packid, out_alpha, N);
    k_mlp<<<(P + 255) / 256, 256, 0, stream>>>(data, W1bf, W2bf, hpe, packid, preact, P);
    k_comp<<<B / 4, 256, 0, stream>>>(rays_d, intrs, preact, packid, cnt, roff, b2,
                                      out, B, N);
}